// Round 9
// baseline (11040.816 us; speedup 1.0000x reference)
//
#include <hip/hip_runtime.h>

typedef unsigned short u16;
typedef short bf16x8 __attribute__((ext_vector_type(8)));
typedef unsigned short ushort8 __attribute__((ext_vector_type(8)));
typedef unsigned short us4 __attribute__((ext_vector_type(4)));
typedef unsigned u32x4 __attribute__((ext_vector_type(4)));

#define DEVI __device__ __forceinline__

enum { BB = 4, TT = 512, HH = 1024, VV = 32000, H4 = 4096, NWG = 256 };

DEVI u16 f2bf(float f) {
    union { float f; unsigned u; } x; x.f = f;
    unsigned r = x.u + 0x7fff + ((x.u >> 16) & 1);
    return (u16)(r >> 16);
}
DEVI float bf2f(u16 u) {
    union { unsigned u; float f; } x; x.u = ((unsigned)u) << 16;
    return x.f;
}
DEVI float sigm(float x) { return 1.f / (1.f + __expf(-x)); }

// device-scope (cross-XCD coherent) relaxed accesses
DEVI unsigned ald_u32(const unsigned* p) { return __hip_atomic_load(p, __ATOMIC_RELAXED, __HIP_MEMORY_SCOPE_AGENT); }
DEVI void ast_u32(unsigned* p, unsigned v) { __hip_atomic_store(p, v, __ATOMIC_RELAXED, __HIP_MEMORY_SCOPE_AGENT); }

// wide coherent load: 16B per fabric request, bypass L1+L2 (device-coherent)
DEVI void ld4cc(const unsigned* p, u32x4* out) {
    asm volatile("global_load_dwordx4 %0, %1, off sc0 sc1" : "=v"(*out) : "v"(p));
}
// XCD-local wide access: bypass L1 only, served by this XCD's L2
DEVI void ld4sc0(const unsigned* p, u32x4* out) {
    asm volatile("global_load_dwordx4 %0, %1, off sc0" : "=v"(*out) : "v"(p));
}
DEVI void st4sc0(unsigned* p, u32x4 v) {
    asm volatile("global_store_dwordx4 %0, %1, off sc0" :: "v"(p), "v"(v) : "memory");
}

DEVI int get_xcd() {
    unsigned x;
    asm volatile("s_getreg_b32 %0, hwreg(HW_REG_XCC_ID)" : "=s"(x));
    return (int)(x & 7);
}

// ---- r8 known-good direct coherent staging (fallback path) ----
DEVI void stage_region(const unsigned* src, unsigned want, u16 (*dst)[1024], int tid) {
    const unsigned* p0 = src + 0 * 1024 + tid * 4;
    const unsigned* p1 = src + 1 * 1024 + tid * 4;
    const unsigned* p2 = src + 2 * 1024 + tid * 4;
    const unsigned* p3 = src + 3 * 1024 + tid * 4;
    u32x4 v0, v1, v2, v3;
    ld4cc(p0, &v0); ld4cc(p1, &v1); ld4cc(p2, &v2); ld4cc(p3, &v3);
    asm volatile("s_waitcnt vmcnt(0)" ::: "memory");
    __builtin_amdgcn_sched_barrier(0);
    for (;;) {
        bool o0 = ((v0[0] >> 16) == want) & ((v0[1] >> 16) == want) & ((v0[2] >> 16) == want) & ((v0[3] >> 16) == want);
        bool o1 = ((v1[0] >> 16) == want) & ((v1[1] >> 16) == want) & ((v1[2] >> 16) == want) & ((v1[3] >> 16) == want);
        bool o2 = ((v2[0] >> 16) == want) & ((v2[1] >> 16) == want) & ((v2[2] >> 16) == want) & ((v2[3] >> 16) == want);
        bool o3 = ((v3[0] >> 16) == want) & ((v3[1] >> 16) == want) & ((v3[2] >> 16) == want) & ((v3[3] >> 16) == want);
        if (o0 & o1 & o2 & o3) break;
        __builtin_amdgcn_s_sleep(2);
        if (!o0) ld4cc(p0, &v0);
        if (!o1) ld4cc(p1, &v1);
        if (!o2) ld4cc(p2, &v2);
        if (!o3) ld4cc(p3, &v3);
        asm volatile("s_waitcnt vmcnt(0)" ::: "memory");
        __builtin_amdgcn_sched_barrier(0);
    }
    *(us4*)&dst[0][tid * 4] = (us4){(u16)v0[0], (u16)v0[1], (u16)v0[2], (u16)v0[3]};
    *(us4*)&dst[1][tid * 4] = (us4){(u16)v1[0], (u16)v1[1], (u16)v1[2], (u16)v1[3]};
    *(us4*)&dst[2][tid * 4] = (us4){(u16)v2[0], (u16)v2[1], (u16)v2[2], (u16)v2[3]};
    *(us4*)&dst[3][tid * 4] = (us4){(u16)v3[0], (u16)v3[1], (u16)v3[2], (u16)v3[3]};
}

// ---- gateway: poll G coherently, republish to XCD mailbox (sc0 -> local L2) + own LDS ----
DEVI void gw_stage(const unsigned* gl, unsigned* mb, unsigned want, u16 (*dst)[1024], int tid) {
    const unsigned* p0 = gl + 0 * 1024 + tid * 4;
    const unsigned* p1 = gl + 1 * 1024 + tid * 4;
    const unsigned* p2 = gl + 2 * 1024 + tid * 4;
    const unsigned* p3 = gl + 3 * 1024 + tid * 4;
    u32x4 v0, v1, v2, v3;
    ld4cc(p0, &v0); ld4cc(p1, &v1); ld4cc(p2, &v2); ld4cc(p3, &v3);
    asm volatile("s_waitcnt vmcnt(0)" ::: "memory");
    __builtin_amdgcn_sched_barrier(0);
    for (;;) {
        bool o0 = ((v0[0] >> 16) == want) & ((v0[1] >> 16) == want) & ((v0[2] >> 16) == want) & ((v0[3] >> 16) == want);
        bool o1 = ((v1[0] >> 16) == want) & ((v1[1] >> 16) == want) & ((v1[2] >> 16) == want) & ((v1[3] >> 16) == want);
        bool o2 = ((v2[0] >> 16) == want) & ((v2[1] >> 16) == want) & ((v2[2] >> 16) == want) & ((v2[3] >> 16) == want);
        bool o3 = ((v3[0] >> 16) == want) & ((v3[1] >> 16) == want) & ((v3[2] >> 16) == want) & ((v3[3] >> 16) == want);
        if (o0 & o1 & o2 & o3) break;
        __builtin_amdgcn_s_sleep(1);
        if (!o0) ld4cc(p0, &v0);
        if (!o1) ld4cc(p1, &v1);
        if (!o2) ld4cc(p2, &v2);
        if (!o3) ld4cc(p3, &v3);
        asm volatile("s_waitcnt vmcnt(0)" ::: "memory");
        __builtin_amdgcn_sched_barrier(0);
    }
    st4sc0(mb + 0 * 1024 + tid * 4, v0);
    st4sc0(mb + 1 * 1024 + tid * 4, v1);
    st4sc0(mb + 2 * 1024 + tid * 4, v2);
    st4sc0(mb + 3 * 1024 + tid * 4, v3);
    *(us4*)&dst[0][tid * 4] = (us4){(u16)v0[0], (u16)v0[1], (u16)v0[2], (u16)v0[3]};
    *(us4*)&dst[1][tid * 4] = (us4){(u16)v1[0], (u16)v1[1], (u16)v1[2], (u16)v1[3]};
    *(us4*)&dst[2][tid * 4] = (us4){(u16)v2[0], (u16)v2[1], (u16)v2[2], (u16)v2[3]};
    *(us4*)&dst[3][tid * 4] = (us4){(u16)v3[0], (u16)v3[1], (u16)v3[2], (u16)v3[3]};
}

// ---- consumer: poll XCD mailbox via sc0 (local L2, no fabric); timeout -> false ----
DEVI bool mb_stage(const unsigned* mb, unsigned want, u16 (*dst)[1024], int tid) {
    const unsigned* p0 = mb + 0 * 1024 + tid * 4;
    const unsigned* p1 = mb + 1 * 1024 + tid * 4;
    const unsigned* p2 = mb + 2 * 1024 + tid * 4;
    const unsigned* p3 = mb + 3 * 1024 + tid * 4;
    u32x4 v0, v1, v2, v3;
    ld4sc0(p0, &v0); ld4sc0(p1, &v1); ld4sc0(p2, &v2); ld4sc0(p3, &v3);
    asm volatile("s_waitcnt vmcnt(0)" ::: "memory");
    __builtin_amdgcn_sched_barrier(0);
    int tries = 0;
    for (;;) {
        bool o0 = ((v0[0] >> 16) == want) & ((v0[1] >> 16) == want) & ((v0[2] >> 16) == want) & ((v0[3] >> 16) == want);
        bool o1 = ((v1[0] >> 16) == want) & ((v1[1] >> 16) == want) & ((v1[2] >> 16) == want) & ((v1[3] >> 16) == want);
        bool o2 = ((v2[0] >> 16) == want) & ((v2[1] >> 16) == want) & ((v2[2] >> 16) == want) & ((v2[3] >> 16) == want);
        bool o3 = ((v3[0] >> 16) == want) & ((v3[1] >> 16) == want) & ((v3[2] >> 16) == want) & ((v3[3] >> 16) == want);
        if (o0 & o1 & o2 & o3) break;
        if (++tries > 1500) return false;
        __builtin_amdgcn_s_sleep(1);
        if (!o0) ld4sc0(p0, &v0);
        if (!o1) ld4sc0(p1, &v1);
        if (!o2) ld4sc0(p2, &v2);
        if (!o3) ld4sc0(p3, &v3);
        asm volatile("s_waitcnt vmcnt(0)" ::: "memory");
        __builtin_amdgcn_sched_barrier(0);
    }
    *(us4*)&dst[0][tid * 4] = (us4){(u16)v0[0], (u16)v0[1], (u16)v0[2], (u16)v0[3]};
    *(us4*)&dst[1][tid * 4] = (us4){(u16)v1[0], (u16)v1[1], (u16)v1[2], (u16)v1[3]};
    *(us4*)&dst[2][tid * 4] = (us4){(u16)v2[0], (u16)v2[1], (u16)v2[2], (u16)v2[3]};
    *(us4*)&dst[3][tid * 4] = (us4){(u16)v3[0], (u16)v3[1], (u16)v3[2], (u16)v3[3]};
    return true;
}

// ---------------- transpose + cast: src [R][C] f32 -> dst [C][R] bf16 ----------------
__global__ void transpose_cast(const float* __restrict__ src, u16* __restrict__ dst, int R, int C) {
    __shared__ float tile[32][33];
    int c0 = blockIdx.x * 32, r0 = blockIdx.y * 32;
    int x = threadIdx.x, y = threadIdx.y;
#pragma unroll
    for (int i = 0; i < 32; i += 8) tile[y + i][x] = src[(size_t)(r0 + y + i) * C + c0 + x];
    __syncthreads();
#pragma unroll
    for (int i = 0; i < 32; i += 8) dst[(size_t)(c0 + y + i) * R + r0 + x] = f2bf(tile[x][y + i]);
}

__global__ void cast_bf16(const float* __restrict__ src, u16* __restrict__ dst, int n) {
    int i = blockIdx.x * 256 + threadIdx.x;
    if (i < n) dst[i] = f2bf(src[i]);
}

__global__ void zero_buf(float* p, int n) {
    int i = blockIdx.x * 256 + threadIdx.x;
    if (i < n) p[i] = 0.f;
}

// ---------------- gather + layernorm (layer 0 input) ----------------
__global__ __launch_bounds__(256) void gather_ln(const int* __restrict__ x, const float* __restrict__ emb,
                                                 const float* __restrict__ g, const float* __restrict__ b,
                                                 float* __restrict__ xe, u16* __restrict__ xn0) {
    int t = blockIdx.x, bb = blockIdx.y;
    int row = x[bb * TT + t];
    const float* e = emb + (size_t)row * HH;
    float v[4]; float s = 0.f, s2 = 0.f;
#pragma unroll
    for (int p = 0; p < 4; p++) { v[p] = e[p * 256 + threadIdx.x]; s += v[p]; s2 += v[p] * v[p]; }
    __shared__ float ls[4], ls2[4];
    for (int off = 32; off; off >>= 1) { s += __shfl_xor(s, off); s2 += __shfl_xor(s2, off); }
    int w = threadIdx.x >> 6, lane = threadIdx.x & 63;
    if (lane == 0) { ls[w] = s; ls2[w] = s2; }
    __syncthreads();
    s = ls[0] + ls[1] + ls[2] + ls[3];
    s2 = ls2[0] + ls2[1] + ls2[2] + ls2[3];
    float mu = s * (1.f / HH);
    float var = s2 * (1.f / HH) - mu * mu;
    float rs = rsqrtf(var + 1e-6f);
    size_t base = ((size_t)t * BB + bb) * HH;
#pragma unroll
    for (int p = 0; p < 4; p++) {
        int j = p * 256 + threadIdx.x;
        xe[base + j] = v[p];
        xn0[base + j] = f2bf((v[p] - mu) * rs * g[j] + b[j]);
    }
}

// ---------------- MFMA GEMM: C[M,N] = A[M,K](bf16) * Bt[N,K](bf16)^T ----------------
template <int MODE>
__global__ __launch_bounds__(256) void gemm_bt(const u16* __restrict__ A, const u16* __restrict__ Bt,
                                               float* __restrict__ Cf, u16* __restrict__ Cb,
                                               const float* __restrict__ bias, int M, int N, int K) {
    __shared__ u16 ldsA[128 * 40];
    __shared__ u16 ldsB[128 * 40];
    typedef float f32x4 __attribute__((ext_vector_type(4)));
    const int tid = threadIdx.x;
    const int m0 = blockIdx.y * 128, n0 = blockIdx.x * 128;
    const int lane = tid & 63, wid = tid >> 6;
    const int wr = wid >> 1, wc = wid & 1;
    const int l15 = lane & 15, lk = (lane >> 4) * 8;
    f32x4 acc[4][4];
#pragma unroll
    for (int a = 0; a < 4; a++)
#pragma unroll
        for (int b = 0; b < 4; b++) { f32x4 z = {0.f, 0.f, 0.f, 0.f}; acc[a][b] = z; }

    const int arow = tid >> 2, acol = (tid & 3) * 8;
    for (int k0 = 0; k0 < K; k0 += 32) {
#pragma unroll
        for (int p = 0; p < 2; p++) {
            int r = arow + p * 64;
            ushort8 va = *(const ushort8*)(A + (size_t)(m0 + r) * K + k0 + acol);
            *(ushort8*)&ldsA[r * 40 + acol] = va;
            ushort8 vb = *(const ushort8*)(Bt + (size_t)(n0 + r) * K + k0 + acol);
            *(ushort8*)&ldsB[r * 40 + acol] = vb;
        }
        __syncthreads();
        bf16x8 af[4], bfr[4];
#pragma unroll
        for (int mi = 0; mi < 4; mi++) af[mi] = *(const bf16x8*)&ldsA[(wr * 64 + mi * 16 + l15) * 40 + lk];
#pragma unroll
        for (int ni = 0; ni < 4; ni++) bfr[ni] = *(const bf16x8*)&ldsB[(wc * 64 + ni * 16 + l15) * 40 + lk];
#pragma unroll
        for (int mi = 0; mi < 4; mi++)
#pragma unroll
            for (int ni = 0; ni < 4; ni++)
                acc[mi][ni] = __builtin_amdgcn_mfma_f32_16x16x32_bf16(af[mi], bfr[ni], acc[mi][ni], 0, 0, 0);
        __syncthreads();
    }
#pragma unroll
    for (int mi = 0; mi < 4; mi++) {
#pragma unroll
        for (int ni = 0; ni < 4; ni++) {
#pragma unroll
            for (int r = 0; r < 4; r++) {
                int gr = m0 + wr * 64 + mi * 16 + (lane >> 4) * 4 + r;
                int gc = n0 + wc * 64 + ni * 16 + l15;
                float v = acc[mi][ni][r];
                if (MODE == 0) {
                    Cf[(size_t)gr * N + gc] = v + bias[gc];
                } else if (MODE == 1) {
                    float u = v + bias[gc];
                    Cb[(size_t)gr * N + gc] = f2bf(u > 0.f ? u : 0.f);
                } else if (MODE == 2) {
                    Cf[(size_t)gr * N + gc] += v;
                } else {
                    int b = gr & 3, t = gr >> 2;
                    Cf[((size_t)b * TT + t) * VV + gc] = v;
                }
            }
        }
    }
}

// ---------------- persistent recurrence kernel (two-level XCD broadcast, real XCC_ID) ----------------
// G layout (u32): h0[4][4096] | h1[4][4096] | y0bf[4][4096]  (49152 u32)
// mbox: 8 per-XCD mirrors of G. One gateway WG per XCD (atomicCAS-elected) polls G
// coherently and republishes via sc0 into its local L2; consumers poll mailbox sc0-only.
__global__ __launch_bounds__(256, 1) void lstm_persist(
    const u16* __restrict__ Wh0, const u16* __restrict__ Wx1, const u16* __restrict__ Wh1,
    const u16* __restrict__ Wo0, const float* __restrict__ pz_all,
    const float* __restrict__ xe, const float* __restrict__ ff0,
    const float* __restrict__ lng, const float* __restrict__ lnb,
    const float* __restrict__ bl, const float* __restrict__ bo,
    float* __restrict__ y0_all, u16* __restrict__ xn1, u16* __restrict__ H1bf,
    unsigned* __restrict__ G, unsigned* __restrict__ mbox, unsigned* __restrict__ claim) {
    __shared__ u16 lsWh0[4][4][1024];   // 32 KB
    __shared__ u16 lsWx1[4][4][1024];   // 32 KB
    __shared__ u16 lsWh1[4][4][1024];   // 32 KB
    __shared__ u16 lsWo0[4][1024];      // 8 KB
    __shared__ u16 sh0[4][1024];        // 8 KB
    __shared__ u16 sh1[4][1024];        // 8 KB
    __shared__ u16 shy[4][1024];        // 8 KB
    __shared__ float cst[2][4][4];
    __shared__ int sxcd, sgw;

    const int w = blockIdx.x;
    const int tid = threadIdx.x;
    const int v = tid >> 6, lane = tid & 63;
    const int iv = w * 4 + v;
    const int k1 = lane * 8, k2 = 512 + lane * 8;

    unsigned* Gh0 = G;
    unsigned* Gh1 = G + 16384;
    unsigned* Gyb = G + 32768;

    // ---- gateway election on real XCD id ----
    if (tid == 0) {
        int xcd = get_xcd();
        unsigned old = atomicCAS(&claim[xcd * 32], 0u, (unsigned)(w + 1));
        sxcd = xcd;
        sgw = (old == 0) ? 1 : 0;
    }

    // ---- one-time: weights -> LDS ----
#pragma unroll
    for (int g = 0; g < 4; g++) {
        size_t row = (size_t)(g * 1024 + iv) * 1024;
        const uint4* s0 = (const uint4*)(Wh0 + row);
        const uint4* s1 = (const uint4*)(Wx1 + row);
        const uint4* s2 = (const uint4*)(Wh1 + row);
        uint4* d0 = (uint4*)&lsWh0[v][g][0];
        uint4* d1 = (uint4*)&lsWx1[v][g][0];
        uint4* d2 = (uint4*)&lsWh1[v][g][0];
        d0[lane * 2] = s0[lane * 2]; d0[lane * 2 + 1] = s0[lane * 2 + 1];
        d1[lane * 2] = s1[lane * 2]; d1[lane * 2 + 1] = s1[lane * 2 + 1];
        d2[lane * 2] = s2[lane * 2]; d2[lane * 2 + 1] = s2[lane * 2 + 1];
    }
    {
        const uint4* s = (const uint4*)(Wo0 + (size_t)iv * 1024);
        uint4* d = (uint4*)&lsWo0[v][0];
        d[lane * 2] = s[lane * 2]; d[lane * 2 + 1] = s[lane * 2 + 1];
    }
    if (tid < 32) ((float*)cst)[tid] = 0.f;

    // ---- one-time: per-lane LN params (layer 1), biases ----
    float lg[16], lbv[16];
    *(float4*)&lg[0]  = *(const float4*)&lng[1024 + k1];
    *(float4*)&lg[4]  = *(const float4*)&lng[1024 + k1 + 4];
    *(float4*)&lg[8]  = *(const float4*)&lng[1024 + k2];
    *(float4*)&lg[12] = *(const float4*)&lng[1024 + k2 + 4];
    *(float4*)&lbv[0]  = *(const float4*)&lnb[1024 + k1];
    *(float4*)&lbv[4]  = *(const float4*)&lnb[1024 + k1 + 4];
    *(float4*)&lbv[8]  = *(const float4*)&lnb[1024 + k2];
    *(float4*)&lbv[12] = *(const float4*)&lnb[1024 + k2 + 4];
    float bl1r[4];
#pragma unroll
    for (int g = 0; g < 4; g++) bl1r[g] = bl[4096 + g * 1024 + iv];
    const float bor = bo[iv];

    __syncthreads();
    const bool isgw = (sgw != 0);
    unsigned* MB = mbox + (size_t)sxcd * 49152;
    unsigned* Mh0 = MB;
    unsigned* Mh1 = MB + 16384;
    unsigned* Myb = MB + 32768;
    bool use_mb = !isgw;

    for (int s = 0; s < TT + 2; s++) {
        const int t1 = s, t2 = s - 1, t3 = s - 2;
        const bool doP1 = (t1 < TT);
        const bool doP2 = (t2 >= 0 && t2 < TT);
        const bool doP3 = (t3 >= 0 && t3 < TT);
        const bool needH0 = doP1 || doP2;

        // ---- stage cross-wg state into LDS ----
        if (needH0) {
            int sl = ((t1 + 3) & 3) * 4096;
            if (isgw) gw_stage(Gh0 + sl, Mh0 + sl, (unsigned)t1, sh0, tid);
            else if (!use_mb || !mb_stage(Mh0 + sl, (unsigned)t1, sh0, tid)) {
                stage_region(Gh0 + sl, (unsigned)t1, sh0, tid); use_mb = false;
            }
        }
        if (doP3) {
            int sl = ((t3 + 3) & 3) * 4096;
            if (isgw) gw_stage(Gh1 + sl, Mh1 + sl, (unsigned)t3, sh1, tid);
            else if (!use_mb || !mb_stage(Mh1 + sl, (unsigned)t3, sh1, tid)) {
                stage_region(Gh1 + sl, (unsigned)t3, sh1, tid); use_mb = false;
            }
            int sy = (t3 & 3) * 4096;
            if (isgw) gw_stage(Gyb + sy, Myb + sy, (unsigned)(t3 + 1), shy, tid);
            else if (!use_mb || !mb_stage(Myb + sy, (unsigned)(t3 + 1), shy, tid)) {
                stage_region(Gyb + sy, (unsigned)(t3 + 1), shy, tid); use_mb = false;
            }
        }
        float pzv[4] = {0.f, 0.f, 0.f, 0.f}, xev = 0.f, ffv = 0.f;
        if (lane < 4) {
            if (doP1) {
                size_t base = ((size_t)t1 * 4 + lane) * 4096 + iv;
                pzv[0] = pz_all[base];        pzv[1] = pz_all[base + 1024];
                pzv[2] = pz_all[base + 2048]; pzv[3] = pz_all[base + 3072];
            }
            if (doP2) {
                size_t base = ((size_t)t2 * 4 + lane) * 1024 + iv;
                xev = xe[base]; ffv = ff0[base];
            }
        }
        __syncthreads();

        // ---- P3: LN(y0[t3]) + layer-1 gates ----
        if (doP3) {
            float xn[4][16];
#pragma unroll
            for (int b = 0; b < 4; b++) {
                ushort8 ya = *(const ushort8*)&shy[b][k1];
                ushort8 yc = *(const ushort8*)&shy[b][k2];
#pragma unroll
                for (int m = 0; m < 8; m++) { xn[b][m] = bf2f(ya[m]); xn[b][8 + m] = bf2f(yc[m]); }
                float sm = 0.f, sq = 0.f;
#pragma unroll
                for (int m = 0; m < 16; m++) { sm += xn[b][m]; sq += xn[b][m] * xn[b][m]; }
#pragma unroll
                for (int o = 1; o < 64; o <<= 1) { sm += __shfl_xor(sm, o); sq += __shfl_xor(sq, o); }
                float mu = sm * (1.f / 1024.f);
                float rs = rsqrtf(sq * (1.f / 1024.f) - mu * mu + 1e-6f);
#pragma unroll
                for (int m = 0; m < 16; m++) xn[b][m] = (xn[b][m] - mu) * rs * lg[m] + lbv[m];
            }
            float h1v[4][16];
#pragma unroll
            for (int b = 0; b < 4; b++) {
                ushort8 a = *(const ushort8*)&sh1[b][k1];
                ushort8 c = *(const ushort8*)&sh1[b][k2];
#pragma unroll
                for (int m = 0; m < 8; m++) { h1v[b][m] = bf2f(a[m]); h1v[b][8 + m] = bf2f(c[m]); }
            }
            float za[4][4] = {};
#pragma unroll
            for (int g = 0; g < 4; g++) {
                ushort8 xa = *(const ushort8*)&lsWx1[v][g][k1];
                ushort8 xb = *(const ushort8*)&lsWx1[v][g][k2];
                ushort8 ha = *(const ushort8*)&lsWh1[v][g][k1];
                ushort8 hb = *(const ushort8*)&lsWh1[v][g][k2];
#pragma unroll
                for (int m = 0; m < 8; m++) {
                    float x1 = bf2f(xa[m]), x2 = bf2f(xb[m]);
                    float h1 = bf2f(ha[m]), h2 = bf2f(hb[m]);
#pragma unroll
                    for (int b = 0; b < 4; b++)
                        za[g][b] += x1 * xn[b][m] + x2 * xn[b][8 + m] + h1 * h1v[b][m] + h2 * h1v[b][8 + m];
                }
            }
#pragma unroll
            for (int g = 0; g < 4; g++)
#pragma unroll
                for (int b = 0; b < 4; b++)
#pragma unroll
                    for (int o = 1; o < 64; o <<= 1) za[g][b] += __shfl_xor(za[g][b], o);
            if (lane < 4) {
                int b = lane;
                float ig = sigm(za[0][b] + bl1r[0]);
                float fg = sigm(za[1][b] + bl1r[1]);
                float og = sigm(za[2][b] + bl1r[2]);
                float gg = tanhf(za[3][b] + bl1r[3]);
                float c = fg * cst[1][v][b] + ig * gg;
                cst[1][v][b] = c;
                float h = og * tanhf(c);
                u16 hb16 = f2bf(h);
                ast_u32(&Gh1[(t3 & 3) * 4096 + b * 1024 + iv], ((unsigned)(t3 + 1) << 16) | hb16);
                H1bf[(size_t)t3 * 4096 + b * 1024 + iv] = hb16;
            }
            if (w == 0) {
                ushort8 o1, o2;
#pragma unroll
                for (int m = 0; m < 8; m++) { o1[m] = f2bf(xn[v][m]); o2[m] = f2bf(xn[v][8 + m]); }
                *(ushort8*)&xn1[(size_t)t3 * 4096 + v * 1024 + k1] = o1;
                *(ushort8*)&xn1[(size_t)t3 * 4096 + v * 1024 + k2] = o2;
            }
        }

        // ---- P1 (layer-0 gates) + P2 (y0) share the staged h0 ----
        if (needH0) {
            float h0v[4][16];
#pragma unroll
            for (int b = 0; b < 4; b++) {
                ushort8 a = *(const ushort8*)&sh0[b][k1];
                ushort8 c = *(const ushort8*)&sh0[b][k2];
#pragma unroll
                for (int m = 0; m < 8; m++) { h0v[b][m] = bf2f(a[m]); h0v[b][8 + m] = bf2f(c[m]); }
            }
            if (doP1) {
                float zp[4][4] = {};
#pragma unroll
                for (int g = 0; g < 4; g++) {
                    ushort8 ha = *(const ushort8*)&lsWh0[v][g][k1];
                    ushort8 hb = *(const ushort8*)&lsWh0[v][g][k2];
#pragma unroll
                    for (int m = 0; m < 8; m++) {
                        float w1 = bf2f(ha[m]), w2 = bf2f(hb[m]);
#pragma unroll
                        for (int b = 0; b < 4; b++)
                            zp[g][b] += w1 * h0v[b][m] + w2 * h0v[b][8 + m];
                    }
                }
#pragma unroll
                for (int g = 0; g < 4; g++)
#pragma unroll
                    for (int b = 0; b < 4; b++)
#pragma unroll
                        for (int o = 1; o < 64; o <<= 1) zp[g][b] += __shfl_xor(zp[g][b], o);
                if (lane < 4) {
                    int b = lane;
                    float ig = sigm(zp[0][b] + pzv[0]);
                    float fg = sigm(zp[1][b] + pzv[1]);
                    float og = sigm(zp[2][b] + pzv[2]);
                    float gg = tanhf(zp[3][b] + pzv[3]);
                    float c = fg * cst[0][v][b] + ig * gg;
                    cst[0][v][b] = c;
                    float h = og * tanhf(c);
                    ast_u32(&Gh0[(t1 & 3) * 4096 + b * 1024 + iv], ((unsigned)(t1 + 1) << 16) | f2bf(h));
                }
            }
            if (doP2) {
                float acc[4] = {};
                ushort8 oa = *(const ushort8*)&lsWo0[v][k1];
                ushort8 ob = *(const ushort8*)&lsWo0[v][k2];
#pragma unroll
                for (int m = 0; m < 8; m++) {
                    float w1 = bf2f(oa[m]), w2 = bf2f(ob[m]);
#pragma unroll
                    for (int b = 0; b < 4; b++)
                        acc[b] += w1 * h0v[b][m] + w2 * h0v[b][8 + m];
                }
#pragma unroll
                for (int b = 0; b < 4; b++)
#pragma unroll
                    for (int o = 1; o < 64; o <<= 1) acc[b] += __shfl_xor(acc[b], o);
                if (lane < 4) {
                    int b = lane;
                    float yv = acc[b] + xev + ffv + bor;
                    y0_all[((size_t)t2 * 4 + b) * 1024 + iv] = yv;
                    ast_u32(&Gyb[(t2 & 3) * 4096 + b * 1024 + iv],
                            ((unsigned)(t2 + 1) << 16) | f2bf(yv));
                }
            }
        }

        // LDS reuse hazard only: intra-WG barrier (cheap)
        __syncthreads();
    }
}

// ---------------- post-loop elementwise ----------------
__global__ void p1_add(float* __restrict__ y, const float* __restrict__ xe,
                       const float* __restrict__ b2_1, const float* __restrict__ bo_1) {
    int idx = blockIdx.x * 256 + threadIdx.x;
    int j = idx & (HH - 1);
    y[idx] += xe[idx] + b2_1[j] + bo_1[j];
}

__global__ void p2_cast(const float* __restrict__ y, u16* __restrict__ o) {
    int idx = blockIdx.x * 256 + threadIdx.x;
    o[idx] = f2bf(y[idx]);
}

// ---------------- host ----------------
extern "C" void kernel_launch(void* const* d_in, const int* in_sizes, int n_in,
                              void* d_out, int out_size, void* d_ws, size_t ws_size,
                              hipStream_t stream) {
    const int* x = (const int*)d_in[0];
    const float* emb = (const float*)d_in[1];
    const float* ln_g = (const float*)d_in[2];
    const float* ln_b = (const float*)d_in[3];
    const float* Wl = (const float*)d_in[4];
    const float* bl = (const float*)d_in[5];
    const float* Wo = (const float*)d_in[6];
    const float* bo = (const float*)d_in[7];
    const float* W1 = (const float*)d_in[8];
    const float* b1 = (const float*)d_in[9];
    const float* W2 = (const float*)d_in[10];
    const float* b2 = (const float*)d_in[11];
    float* out = (float*)d_out;

    char* wp = (char*)d_ws;
    auto alloc = [&](size_t bytes) { void* p = wp; wp += (bytes + 255) & ~(size_t)255; return p; };
    const size_t MBT = (size_t)TT * BB;  // 2048 rows
    float* xe     = (float*)alloc(MBT * HH * 4);
    float* pre_z0 = (float*)alloc(MBT * H4 * 4);
    float* ff0    = (float*)alloc(MBT * HH * 4);
    float* y0_all = (float*)alloc(MBT * HH * 4);
    u16* xn0      = (u16*)alloc(MBT * HH * 2);
    u16* xn1      = (u16*)alloc(MBT * HH * 2);
    u16* U0       = (u16*)alloc(MBT * H4 * 2);
    u16* U1       = (u16*)alloc(MBT * H4 * 2);
    u16* H1bf     = (u16*)alloc(MBT * HH * 2);
    u16* Y1bf     = (u16*)alloc(MBT * HH * 2);
    // zeroed span: G (49152) | mbox (8*49152) | claim (256)  = 442624 u32
    unsigned* G     = (unsigned*)alloc(442624 * 4);
    unsigned* mbox  = G + 49152;
    unsigned* claim = G + 49152 + 8 * 49152;
    u16* WlxT0 = (u16*)alloc((size_t)H4 * HH * 2);
    u16* WlhT0 = (u16*)alloc((size_t)H4 * HH * 2);
    u16* WlxT1 = (u16*)alloc((size_t)H4 * HH * 2);
    u16* WlhT1 = (u16*)alloc((size_t)H4 * HH * 2);
    u16* Wo0T  = (u16*)alloc((size_t)HH * HH * 2);
    u16* Wo1T  = (u16*)alloc((size_t)HH * HH * 2);
    u16* W10T  = (u16*)alloc((size_t)H4 * HH * 2);
    u16* W11T  = (u16*)alloc((size_t)H4 * HH * 2);
    u16* W20T  = (u16*)alloc((size_t)HH * H4 * 2);
    u16* W21T  = (u16*)alloc((size_t)HH * H4 * 2);
    u16* embB  = (u16*)alloc((size_t)VV * HH * 2);

    dim3 tb(32, 8);
    // Wl: [L][2H][4H]; rows 0..H-1 = x-part, H..2H-1 = h-part
    transpose_cast<<<dim3(128, 32), tb, 0, stream>>>(Wl, WlxT0, HH, H4);
    transpose_cast<<<dim3(128, 32), tb, 0, stream>>>(Wl + 1024 * 4096, WlhT0, HH, H4);
    transpose_cast<<<dim3(128, 32), tb, 0, stream>>>(Wl + 2048 * 4096, WlxT1, HH, H4);
    transpose_cast<<<dim3(128, 32), tb, 0, stream>>>(Wl + 3072 * 4096, WlhT1, HH, H4);
    transpose_cast<<<dim3(32, 32), tb, 0, stream>>>(Wo, Wo0T, HH, HH);
    transpose_cast<<<dim3(32, 32), tb, 0, stream>>>(Wo + 1024 * 1024, Wo1T, HH, HH);
    transpose_cast<<<dim3(128, 32), tb, 0, stream>>>(W1, W10T, HH, H4);
    transpose_cast<<<dim3(128, 32), tb, 0, stream>>>(W1 + 1024 * 4096, W11T, HH, H4);
    transpose_cast<<<dim3(32, 128), tb, 0, stream>>>(W2, W20T, H4, HH);
    transpose_cast<<<dim3(32, 128), tb, 0, stream>>>(W2 + 4096 * 1024, W21T, H4, HH);
    cast_bf16<<<(VV * HH + 255) / 256, 256, 0, stream>>>(emb, embB, VV * HH);
    gather_ln<<<dim3(TT, BB), 256, 0, stream>>>(x, emb, ln_g, ln_b, xe, xn0);

    // Phase A GEMMs (parallel precompute)
    gemm_bt<0><<<dim3(32, 16), 256, 0, stream>>>(xn0, WlxT0, pre_z0, nullptr, bl, 2048, 4096, 1024);
    gemm_bt<1><<<dim3(32, 16), 256, 0, stream>>>(xn0, W10T, nullptr, U0, b1, 2048, 4096, 1024);
    gemm_bt<0><<<dim3(8, 16), 256, 0, stream>>>(U0, W20T, ff0, nullptr, b2, 2048, 1024, 4096);

    // zero G + mbox + claim
    zero_buf<<<1729, 256, 0, stream>>>((float*)G, 442624);

    // Phase B: persistent recurrence (1 wg/CU, tagged dataflow + XCD gateway broadcast)
    lstm_persist<<<NWG, 256, 0, stream>>>(WlhT0, WlxT1, WlhT1, Wo0T, pre_z0, xe, ff0,
                                          ln_g, ln_b, bl, bo, y0_all, xn1, H1bf, G, mbox, claim);

    // Phase C: deferred layer-1 output + logits
    gemm_bt<1><<<dim3(32, 16), 256, 0, stream>>>(xn1, W11T, nullptr, U1, b1 + 4096, 2048, 4096, 1024);
    p1_add<<<8192, 256, 0, stream>>>(y0_all, xe, b2 + 1024, bo + 1024);
    gemm_bt<2><<<dim3(8, 16), 256, 0, stream>>>(U1, W21T, y0_all, nullptr, nullptr, 2048, 1024, 4096);
    gemm_bt<2><<<dim3(8, 16), 256, 0, stream>>>(H1bf, Wo1T, y0_all, nullptr, nullptr, 2048, 1024, 1024);
    p2_cast<<<8192, 256, 0, stream>>>(y0_all, Y1bf);
    gemm_bt<3><<<dim3(250, 16), 256, 0, stream>>>(Y1bf, embB, out, nullptr, nullptr, 2048, 32000, 1024);
}

// Round 11
// 4031.561 us; speedup vs baseline: 2.7386x; 2.7386x over previous
//
#include <hip/hip_runtime.h>

typedef unsigned short u16;
typedef short bf16x8 __attribute__((ext_vector_type(8)));
typedef unsigned short ushort8 __attribute__((ext_vector_type(8)));
typedef unsigned short us4 __attribute__((ext_vector_type(4)));
typedef unsigned u32x4 __attribute__((ext_vector_type(4)));
typedef float fx4 __attribute__((ext_vector_type(4)));

#define DEVI __device__ __forceinline__

enum { BB = 4, TT = 512, HH = 1024, VV = 32000, H4 = 4096 };
enum { WSTR = 1032 };  // u16 row stride for LDS weight/stage arrays (16B-aligned, bank-spread)

DEVI u16 f2bf(float f) {
    union { float f; unsigned u; } x; x.f = f;
    unsigned r = x.u + 0x7fff + ((x.u >> 16) & 1);
    return (u16)(r >> 16);
}
DEVI float bf2f(u16 u) {
    union { unsigned u; float f; } x; x.u = ((unsigned)u) << 16;
    return x.f;
}
DEVI float sigm(float x) { return 1.f / (1.f + __expf(-x)); }

DEVI unsigned ald_u32(const unsigned* p) { return __hip_atomic_load(p, __ATOMIC_RELAXED, __HIP_MEMORY_SCOPE_AGENT); }
DEVI void ast_u32(unsigned* p, unsigned v) { __hip_atomic_store(p, v, __ATOMIC_RELAXED, __HIP_MEMORY_SCOPE_AGENT); }

DEVI void ld4cc(const unsigned* p, u32x4* out) {
    asm volatile("global_load_dwordx4 %0, %1, off sc0 sc1" : "=v"(*out) : "v"(p));
}

// poll a 4096-word tagged region ([4][1024] b-major) into LDS st[4][WSTR] (bf16 payloads)
DEVI void poll4096(const unsigned* base, unsigned want, u16* st, int tid) {
    const unsigned* p0 = base + tid * 8;
    const unsigned* p1 = p0 + 4;
    u32x4 v0, v1;
    ld4cc(p0, &v0); ld4cc(p1, &v1);
    asm volatile("s_waitcnt vmcnt(0)" ::: "memory");
    __builtin_amdgcn_sched_barrier(0);
    for (;;) {
        bool o0 = ((v0[0]>>16)==want)&((v0[1]>>16)==want)&((v0[2]>>16)==want)&((v0[3]>>16)==want);
        bool o1 = ((v1[0]>>16)==want)&((v1[1]>>16)==want)&((v1[2]>>16)==want)&((v1[3]>>16)==want);
        if (o0 & o1) break;
        __builtin_amdgcn_s_sleep(1);
        if (!o0) ld4cc(p0, &v0);
        if (!o1) ld4cc(p1, &v1);
        asm volatile("s_waitcnt vmcnt(0)" ::: "memory");
        __builtin_amdgcn_sched_barrier(0);
    }
    int wi = tid * 8;
    u16* d = st + (wi >> 10) * WSTR + (wi & 1023);
    *(us4*)d       = (us4){(u16)v0[0], (u16)v0[1], (u16)v0[2], (u16)v0[3]};
    *(us4*)(d + 4) = (us4){(u16)v1[0], (u16)v1[1], (u16)v1[2], (u16)v1[3]};
}

DEVI unsigned poll_word(const unsigned* p, unsigned want) {
    unsigned v = ald_u32(p);
    while ((v >> 16) != want) { __builtin_amdgcn_s_sleep(1); v = ald_u32(p); }
    return v & 0xFFFFu;
}

// 64-row gate MFMA: D[64 rows][4 cols] = W(LDS) @ h(LDS bf16). 8 waves: wave wv
// handles rowtile wv&3, K-half wv>>2. Partials to fb[kh*256 + lr*4 + col].
DEVI void gates64(const u16* wl, const u16* st, float* fb, int tid) {
    int lane = tid & 63, wv = tid >> 6;
    int rt = wv & 3, kh = wv >> 2;
    fx4 acc = {0.f, 0.f, 0.f, 0.f};
    int aoff = (rt * 16 + (lane & 15)) * WSTR + (lane >> 4) * 8;
    int boff = (lane & 3) * WSTR + (lane >> 4) * 8;
#pragma unroll
    for (int kt = 0; kt < 16; kt++) {
        int k0 = (kh * 16 + kt) * 32;
        bf16x8 a = *(const bf16x8*)(wl + aoff + k0);
        bf16x8 b = *(const bf16x8*)(st + boff + k0);
        acc = __builtin_amdgcn_mfma_f32_16x16x32_bf16(a, b, acc, 0, 0, 0);
    }
    int col = lane & 15;
    if (col < 4) {
        int r0 = rt * 16 + (lane >> 4) * 4;
#pragma unroll
        for (int ri = 0; ri < 4; ri++) fb[kh * 256 + (r0 + ri) * 4 + col] = acc[ri];
    }
}

// ---------------- transpose + cast: src [R][C] f32 -> dst [C][R] bf16 ----------------
__global__ void transpose_cast(const float* __restrict__ src, u16* __restrict__ dst, int R, int C) {
    __shared__ float tile[32][33];
    int c0 = blockIdx.x * 32, r0 = blockIdx.y * 32;
    int x = threadIdx.x, y = threadIdx.y;
#pragma unroll
    for (int i = 0; i < 32; i += 8) tile[y + i][x] = src[(size_t)(r0 + y + i) * C + c0 + x];
    __syncthreads();
#pragma unroll
    for (int i = 0; i < 32; i += 8) dst[(size_t)(c0 + y + i) * R + r0 + x] = f2bf(tile[x][y + i]);
}

__global__ void cast_bf16(const float* __restrict__ src, u16* __restrict__ dst, int n) {
    int i = blockIdx.x * 256 + threadIdx.x;
    if (i < n) dst[i] = f2bf(src[i]);
}

__global__ void zero_buf(float* p, int n) {
    int i = blockIdx.x * 256 + threadIdx.x;
    if (i < n) p[i] = 0.f;
}

// ---------------- gather + layernorm (layer 0 input) ----------------
__global__ __launch_bounds__(256) void gather_ln(const int* __restrict__ x, const float* __restrict__ emb,
                                                 const float* __restrict__ g, const float* __restrict__ b,
                                                 float* __restrict__ xe, u16* __restrict__ xn0) {
    int t = blockIdx.x, bb = blockIdx.y;
    int row = x[bb * TT + t];
    const float* e = emb + (size_t)row * HH;
    float v[4]; float s = 0.f, s2 = 0.f;
#pragma unroll
    for (int p = 0; p < 4; p++) { v[p] = e[p * 256 + threadIdx.x]; s += v[p]; s2 += v[p] * v[p]; }
    __shared__ float ls[4], ls2[4];
    for (int off = 32; off; off >>= 1) { s += __shfl_xor(s, off); s2 += __shfl_xor(s2, off); }
    int w = threadIdx.x >> 6, lane = threadIdx.x & 63;
    if (lane == 0) { ls[w] = s; ls2[w] = s2; }
    __syncthreads();
    s = ls[0] + ls[1] + ls[2] + ls[3];
    s2 = ls2[0] + ls2[1] + ls2[2] + ls2[3];
    float mu = s * (1.f / HH);
    float var = s2 * (1.f / HH) - mu * mu;
    float rs = rsqrtf(var + 1e-6f);
    size_t base = ((size_t)t * BB + bb) * HH;
#pragma unroll
    for (int p = 0; p < 4; p++) {
        int j = p * 256 + threadIdx.x;
        xe[base + j] = v[p];
        xn0[base + j] = f2bf((v[p] - mu) * rs * g[j] + b[j]);
    }
}

// ---------------- MFMA GEMM: C[M,N] = A[M,K](bf16) * Bt[N,K](bf16)^T ----------------
template <int MODE>
__global__ __launch_bounds__(256) void gemm_bt(const u16* __restrict__ A, const u16* __restrict__ Bt,
                                               float* __restrict__ Cf, u16* __restrict__ Cb,
                                               const float* __restrict__ bias, int M, int N, int K) {
    __shared__ u16 ldsA[128 * 40];
    __shared__ u16 ldsB[128 * 40];
    const int tid = threadIdx.x;
    const int m0 = blockIdx.y * 128, n0 = blockIdx.x * 128;
    const int lane = tid & 63, wid = tid >> 6;
    const int wr = wid >> 1, wc = wid & 1;
    const int l15 = lane & 15, lk = (lane >> 4) * 8;
    fx4 acc[4][4];
#pragma unroll
    for (int a = 0; a < 4; a++)
#pragma unroll
        for (int b = 0; b < 4; b++) { fx4 z = {0.f, 0.f, 0.f, 0.f}; acc[a][b] = z; }

    const int arow = tid >> 2, acol = (tid & 3) * 8;
    for (int k0 = 0; k0 < K; k0 += 32) {
#pragma unroll
        for (int p = 0; p < 2; p++) {
            int r = arow + p * 64;
            ushort8 va = *(const ushort8*)(A + (size_t)(m0 + r) * K + k0 + acol);
            *(ushort8*)&ldsA[r * 40 + acol] = va;
            ushort8 vb = *(const ushort8*)(Bt + (size_t)(n0 + r) * K + k0 + acol);
            *(ushort8*)&ldsB[r * 40 + acol] = vb;
        }
        __syncthreads();
        bf16x8 af[4], bfr[4];
#pragma unroll
        for (int mi = 0; mi < 4; mi++) af[mi] = *(const bf16x8*)&ldsA[(wr * 64 + mi * 16 + l15) * 40 + lk];
#pragma unroll
        for (int ni = 0; ni < 4; ni++) bfr[ni] = *(const bf16x8*)&ldsB[(wc * 64 + ni * 16 + l15) * 40 + lk];
#pragma unroll
        for (int mi = 0; mi < 4; mi++)
#pragma unroll
            for (int ni = 0; ni < 4; ni++)
                acc[mi][ni] = __builtin_amdgcn_mfma_f32_16x16x32_bf16(af[mi], bfr[ni], acc[mi][ni], 0, 0, 0);
        __syncthreads();
    }
#pragma unroll
    for (int mi = 0; mi < 4; mi++) {
#pragma unroll
        for (int ni = 0; ni < 4; ni++) {
#pragma unroll
            for (int r = 0; r < 4; r++) {
                int gr = m0 + wr * 64 + mi * 16 + (lane >> 4) * 4 + r;
                int gc = n0 + wc * 64 + ni * 16 + l15;
                float v = acc[mi][ni][r];
                if (MODE == 0) {
                    Cf[(size_t)gr * N + gc] = v + bias[gc];
                } else if (MODE == 1) {
                    float u = v + bias[gc];
                    Cb[(size_t)gr * N + gc] = f2bf(u > 0.f ? u : 0.f);
                } else if (MODE == 2) {
                    Cf[(size_t)gr * N + gc] += v;
                } else {
                    int b = gr & 3, t = gr >> 2;
                    Cf[((size_t)b * TT + t) * VV + gc] = v;
                }
            }
        }
    }
}

// ---------------- Phase B: 3-stage pipelined dataflow ----------------
// Ring layout in R (u32): RH0[4][4096] | RH1[4][4096] | RPART[4][1024] | RXN[16][4096]
//                        | RZX[16][16384] | PROGZX[64*32] | PROGL1
// Roles: bid 0..63 = L0 chain; 64..127 = zx1; 128..191 = L1 chain.
__global__ __launch_bounds__(512, 1) void lstm_pipe(
    const u16* __restrict__ Wh0T, const u16* __restrict__ Wo0T,
    const u16* __restrict__ Wx1T, const u16* __restrict__ Wh1T,
    const float* __restrict__ pz_all, const float* __restrict__ xe, const float* __restrict__ ff0,
    const float* __restrict__ lng, const float* __restrict__ lnb,
    const float* __restrict__ bl, const float* __restrict__ bo,
    float* __restrict__ y0_all, u16* __restrict__ xn1, u16* __restrict__ H1bf,
    unsigned* __restrict__ R) {
    __shared__ u16 wlds[64 * WSTR];   // 129 KB weights
    __shared__ u16 stg[4 * WSTR];     // 8.1 KB staged vector (bf16)
    __shared__ float fb[1536];        // partials / zbuf / state

    const int bid = blockIdx.x;
    const int tid = threadIdx.x;
    const int lane = tid & 63, wv = tid >> 6;

    unsigned* RH0 = R;
    unsigned* RH1 = R + 16384;
    unsigned* RPART = R + 32768;
    unsigned* RXN = R + 36864;
    unsigned* RZX = R + 102400;
    unsigned* PROGZX = R + 364544;
    unsigned* PROGL1 = R + 366592;

    if (bid < 64) {
        // ================= L0 chain =================
        const int w = bid;
        {
            int row = tid >> 3, kc = tid & 7;
            int gr = (row >> 4) * 1024 + w * 16 + (row & 15);
            const uint4* s = (const uint4*)(Wh0T + (size_t)gr * 1024 + kc * 128);
            uint4* d = (uint4*)(wlds + row * WSTR + kc * 128);
#pragma unroll
            for (int i = 0; i < 16; i++) d[i] = s[i];
        }
        uint4 woA[2], woB[2];
#pragma unroll
        for (int jj = 0; jj < 2; jj++) {
            const u16* src = Wo0T + (size_t)(w * 16 + wv * 2 + jj) * 1024 + lane * 16;
            woA[jj] = *(const uint4*)src;
            woB[jj] = *(const uint4*)(src + 8);
        }
        float lgR = 0.f, lbR = 0.f, boR = 0.f;
        if (tid < 64) {
            int x = tid >> 2;
            lgR = lng[1024 + w * 16 + x];
            lbR = lnb[1024 + w * 16 + x];
            boR = bo[w * 16 + x];
            fb[1104 + tid] = 0.f;   // c-state
        }
        __syncthreads();

        for (int s = 0; s < TT + 2; s++) {
            const bool doG = (s < TT);
            const bool doY = (s >= 1 && s <= TT);
            const bool doX = (s >= 2);
            if (doX && (s & 7) == 0 && tid < 64) {
                for (;;) {
                    unsigned p = ald_u32(PROGZX + tid * 32);
#pragma unroll
                    for (int off = 1; off < 64; off <<= 1) {
                        unsigned o = (unsigned)__shfl_xor((int)p, off);
                        p = p < o ? p : o;
                    }
                    if ((int)p >= s - 9) break;
                    __builtin_amdgcn_s_sleep(8);
                }
            }
            float pzv[4] = {0.f,0.f,0.f,0.f}, xev = 0.f, ffv = 0.f;
            if (tid < 64) {
                int x = tid >> 2, b = tid & 3;
                if (doG) {
#pragma unroll
                    for (int g = 0; g < 4; g++)
                        pzv[g] = pz_all[((size_t)s * 4 + b) * 4096 + g * 1024 + w * 16 + x];
                }
                if (doY) {
                    size_t base = ((size_t)(s - 1) * 4 + b) * 1024 + w * 16 + x;
                    xev = xe[base]; ffv = ff0[base];
                }
            }
            if (s <= TT) poll4096(RH0 + ((s + 3) & 3) * 4096, (unsigned)s, stg, tid);
            if (doX) {   // partials of y0[s-2], tag s-1
                const unsigned* p = RPART + ((s - 2) & 3) * 1024 + tid * 2;
                unsigned hi = poll_word(p, (unsigned)(s - 1));
                unsigned lo = poll_word(p + 1, (unsigned)(s - 1));
                union { unsigned u; float f; } c; c.u = (hi << 16) | lo;
                fb[576 + tid] = c.f;
            }
            __syncthreads();   // S1
            if (doX && tid < 8) {
                int b = tid & 3, kind = tid >> 2;
                float S = 0.f;
                for (int i = 0; i < 64; i++) S += fb[576 + i * 8 + b * 2 + kind];
                fb[1096 + kind * 4 + b] = S;
            }
            if (doG) gates64(wlds, stg, fb, tid);
            if (doY) {
                float yacc[2][4] = {};
                ushort8 h8[4][2];
#pragma unroll
                for (int b = 0; b < 4; b++) {
                    h8[b][0] = *(const ushort8*)(stg + b * WSTR + lane * 16);
                    h8[b][1] = *(const ushort8*)(stg + b * WSTR + lane * 16 + 8);
                }
#pragma unroll
                for (int jj = 0; jj < 2; jj++) {
                    const ushort8 wA = *(const ushort8*)&woA[jj];
                    const ushort8 wB = *(const ushort8*)&woB[jj];
#pragma unroll
                    for (int m = 0; m < 8; m++) {
                        float wf = bf2f(wA[m]), wg = bf2f(wB[m]);
#pragma unroll
                        for (int b = 0; b < 4; b++)
                            yacc[jj][b] += wf * bf2f(h8[b][0][m]) + wg * bf2f(h8[b][1][m]);
                    }
                }
#pragma unroll
                for (int jj = 0; jj < 2; jj++)
#pragma unroll
                    for (int b = 0; b < 4; b++) {
                        float v = yacc[jj][b];
#pragma unroll
                        for (int off = 1; off < 64; off <<= 1) v += __shfl_xor(v, off);
                        if (lane == 0) fb[512 + (wv * 2 + jj) * 4 + b] = v;
                    }
            }
            __syncthreads();   // S2
            if (tid < 64) {
                int x = tid >> 2, b = tid & 3;
                if (doG) {
                    float z0 = fb[(0*16+x)*4+b] + fb[256+(0*16+x)*4+b] + pzv[0];
                    float z1 = fb[(1*16+x)*4+b] + fb[256+(1*16+x)*4+b] + pzv[1];
                    float z2 = fb[(2*16+x)*4+b] + fb[256+(2*16+x)*4+b] + pzv[2];
                    float z3 = fb[(3*16+x)*4+b] + fb[256+(3*16+x)*4+b] + pzv[3];
                    float ig = sigm(z0), fg = sigm(z1), og = sigm(z2), gg = tanhf(z3);
                    float c = fg * fb[1104 + tid] + ig * gg;
                    fb[1104 + tid] = c;
                    float h = og * tanhf(c);
                    ast_u32(&RH0[(s & 3) * 4096 + b * 1024 + w * 16 + x],
                            ((unsigned)(s + 1) << 16) | f2bf(h));
                }
                if (doY) {
                    float y = fb[512 + x * 4 + b] + xev + ffv + boR;
                    y0_all[((size_t)(s - 1) * 4 + b) * 1024 + w * 16 + x] = y;
                    fb[1168 + ((s - 1) & 1) * 64 + x * 4 + b] = y;
                    float sv = y, sq = y * y;
#pragma unroll
                    for (int off = 4; off < 64; off <<= 1) { sv += __shfl_xor(sv, off); sq += __shfl_xor(sq, off); }
                    if (tid < 4) {
                        unsigned tg = (unsigned)s << 16;
                        unsigned* pb = RPART + ((s - 1) & 3) * 1024 + w * 16 + tid * 4;
                        union { float f; unsigned u; } c1, c2; c1.f = sv; c2.f = sq;
                        ast_u32(pb + 0, tg | (c1.u >> 16));
                        ast_u32(pb + 1, tg | (c1.u & 0xFFFFu));
                        ast_u32(pb + 2, tg | (c2.u >> 16));
                        ast_u32(pb + 3, tg | (c2.u & 0xFFFFu));
                    }
                }
                if (doX) {
                    int u = s - 2;
                    float Ssum = fb[1096 + b], Ssq = fb[1100 + b];
                    float mu = Ssum * (1.f / 1024.f);
                    float rs = rsqrtf(Ssq * (1.f / 1024.f) - mu * mu + 1e-6f);
                    float yv = fb[1168 + (u & 1) * 64 + x * 4 + b];
                    float xnv = (yv - mu) * rs * lgR + lbR;
                    u16 xb = f2bf(xnv);
                    xn1[(size_t)u * 4096 + b * 1024 + w * 16 + x] = xb;
                    ast_u32(&RXN[(u & 15) * 4096 + b * 1024 + w * 16 + x],
                            ((unsigned)(u + 1) << 16) | xb);
                }
            }
            __syncthreads();   // protect fb/stg reuse
        }
    } else if (bid < 128) {
        // ================= zx1 group =================
        const int wz = bid - 64;
        {
            int row = tid >> 3, kc = tid & 7;
            int gr = (row >> 4) * 1024 + wz * 16 + (row & 15);
            const uint4* s = (const uint4*)(Wx1T + (size_t)gr * 1024 + kc * 128);
            uint4* d = (uint4*)(wlds + row * WSTR + kc * 128);
#pragma unroll
            for (int i = 0; i < 16; i++) d[i] = s[i];
        }
        if (tid < 64) fb[1300 + tid] = bl[4096 + (tid >> 4) * 1024 + wz * 16 + (tid & 15)];
        __syncthreads();

        for (int t = 0; t < TT; t++) {
            if ((t & 7) == 0 && tid == 0) {
                while ((int)ald_u32(PROGL1) < t - 6) __builtin_amdgcn_s_sleep(8);
            }
            poll4096(RXN + (t & 15) * 4096, (unsigned)(t + 1), stg, tid);
            __syncthreads();
            gates64(wlds, stg, fb, tid);
            __syncthreads();
            if (tid < 256) {
                int lr = tid >> 2, b = tid & 3;
                float v = fb[lr * 4 + b] + fb[256 + lr * 4 + b] + fb[1300 + lr];
                ast_u32(&RZX[(t & 15) * 16384 + wz * 256 + tid],
                        ((unsigned)(t + 1) << 16) | f2bf(v));
            }
            if (tid == 0) ast_u32(PROGZX + wz * 32, (unsigned)(t + 1));
            __syncthreads();
        }
    } else {
        // ================= L1 chain =================
        const int w1 = bid - 128;
        {
            int row = tid >> 3, kc = tid & 7;
            int gr = (row >> 4) * 1024 + w1 * 16 + (row & 15);
            const uint4* s = (const uint4*)(Wh1T + (size_t)gr * 1024 + kc * 128);
            uint4* d = (uint4*)(wlds + row * WSTR + kc * 128);
#pragma unroll
            for (int i = 0; i < 16; i++) d[i] = s[i];
        }
        if (tid < 64) fb[576 + tid] = 0.f;   // c-state
        __syncthreads();

        for (int v = 0; v < TT; v++) {
            poll4096(RH1 + ((v + 3) & 3) * 4096, (unsigned)v, stg, tid);
            if (tid < 256) {
                const unsigned* p = RZX + (v & 15) * 16384 + w1 * 256 + tid;
                fb[1024 + (v & 1) * 256 + tid] = bf2f((u16)poll_word(p, (unsigned)(v + 1)));
            }
            __syncthreads();
            gates64(wlds, stg, fb, tid);
            __syncthreads();
            if (tid < 64) {
                int x = tid >> 2, b = tid & 3;
                int zb = 1024 + (v & 1) * 256;
                float z0 = fb[(0*16+x)*4+b] + fb[256+(0*16+x)*4+b] + fb[zb + (0*16+x)*4+b];
                float z1 = fb[(1*16+x)*4+b] + fb[256+(1*16+x)*4+b] + fb[zb + (1*16+x)*4+b];
                float z2 = fb[(2*16+x)*4+b] + fb[256+(2*16+x)*4+b] + fb[zb + (2*16+x)*4+b];
                float z3 = fb[(3*16+x)*4+b] + fb[256+(3*16+x)*4+b] + fb[zb + (3*16+x)*4+b];
                float ig = sigm(z0), fg = sigm(z1), og = sigm(z2), gg = tanhf(z3);
                float c = fg * fb[576 + tid] + ig * gg;
                fb[576 + tid] = c;
                float h = og * tanhf(c);
                u16 hb = f2bf(h);
                H1bf[(size_t)v * 4096 + b * 1024 + w1 * 16 + x] = hb;
                ast_u32(&RH1[(v & 3) * 4096 + b * 1024 + w1 * 16 + x],
                        ((unsigned)(v + 1) << 16) | hb);
            }
            if (bid == 128 && tid == 0) ast_u32(PROGL1, (unsigned)(v + 1));
            __syncthreads();
        }
    }
}

// ---------------- post-loop elementwise ----------------
__global__ void p1_add(float* __restrict__ y, const float* __restrict__ xe,
                       const float* __restrict__ b2_1, const float* __restrict__ bo_1) {
    int idx = blockIdx.x * 256 + threadIdx.x;
    int j = idx & (HH - 1);
    y[idx] += xe[idx] + b2_1[j] + bo_1[j];
}

__global__ void p2_cast(const float* __restrict__ y, u16* __restrict__ o) {
    int idx = blockIdx.x * 256 + threadIdx.x;
    o[idx] = f2bf(y[idx]);
}

// ---------------- host ----------------
extern "C" void kernel_launch(void* const* d_in, const int* in_sizes, int n_in,
                              void* d_out, int out_size, void* d_ws, size_t ws_size,
                              hipStream_t stream) {
    const int* x = (const int*)d_in[0];
    const float* emb = (const float*)d_in[1];
    const float* ln_g = (const float*)d_in[2];
    const float* ln_b = (const float*)d_in[3];
    const float* Wl = (const float*)d_in[4];
    const float* bl = (const float*)d_in[5];
    const float* Wo = (const float*)d_in[6];
    const float* bo = (const float*)d_in[7];
    const float* W1 = (const float*)d_in[8];
    const float* b1 = (const float*)d_in[9];
    const float* W2 = (const float*)d_in[10];
    const float* b2 = (const float*)d_in[11];
    float* out = (float*)d_out;

    char* wp = (char*)d_ws;
    auto alloc = [&](size_t bytes) { void* p = wp; wp += (bytes + 255) & ~(size_t)255; return p; };
    const size_t MBT = (size_t)TT * BB;  // 2048 rows
    float* xe     = (float*)alloc(MBT * HH * 4);
    float* pre_z0 = (float*)alloc(MBT * H4 * 4);
    float* ff0    = (float*)alloc(MBT * HH * 4);
    float* y0_all = (float*)alloc(MBT * HH * 4);
    u16* xn0      = (u16*)alloc(MBT * HH * 2);
    u16* xn1      = (u16*)alloc(MBT * HH * 2);
    u16* U0       = (u16*)alloc(MBT * H4 * 2);
    u16* U1       = (u16*)alloc(MBT * H4 * 2);
    u16* H1bf     = (u16*)alloc(MBT * HH * 2);
    u16* Y1bf     = (u16*)alloc(MBT * HH * 2);
    // dataflow rings: RH0 16384 | RH1 16384 | RPART 4096 | RXN 65536 | RZX 262144 | prog 2080
    unsigned* R   = (unsigned*)alloc(366624 * 4);
    u16* WlxT0 = (u16*)alloc((size_t)H4 * HH * 2);
    u16* WlhT0 = (u16*)alloc((size_t)H4 * HH * 2);
    u16* WlxT1 = (u16*)alloc((size_t)H4 * HH * 2);
    u16* WlhT1 = (u16*)alloc((size_t)H4 * HH * 2);
    u16* Wo0T  = (u16*)alloc((size_t)HH * HH * 2);
    u16* Wo1T  = (u16*)alloc((size_t)HH * HH * 2);
    u16* W10T  = (u16*)alloc((size_t)H4 * HH * 2);
    u16* W11T  = (u16*)alloc((size_t)H4 * HH * 2);
    u16* W20T  = (u16*)alloc((size_t)HH * H4 * 2);
    u16* W21T  = (u16*)alloc((size_t)HH * H4 * 2);
    u16* embB  = (u16*)alloc((size_t)VV * HH * 2);

    dim3 tb(32, 8);
    // Wl: [L][2H][4H]; rows 0..H-1 = x-part, H..2H-1 = h-part
    transpose_cast<<<dim3(128, 32), tb, 0, stream>>>(Wl, WlxT0, HH, H4);
    transpose_cast<<<dim3(128, 32), tb, 0, stream>>>(Wl + 1024 * 4096, WlhT0, HH, H4);
    transpose_cast<<<dim3(128, 32), tb, 0, stream>>>(Wl + 2048 * 4096, WlxT1, HH, H4);
    transpose_cast<<<dim3(128, 32), tb, 0, stream>>>(Wl + 3072 * 4096, WlhT1, HH, H4);
    transpose_cast<<<dim3(32, 32), tb, 0, stream>>>(Wo, Wo0T, HH, HH);
    transpose_cast<<<dim3(32, 32), tb, 0, stream>>>(Wo + 1024 * 1024, Wo1T, HH, HH);
    transpose_cast<<<dim3(128, 32), tb, 0, stream>>>(W1, W10T, HH, H4);
    transpose_cast<<<dim3(128, 32), tb, 0, stream>>>(W1 + 1024 * 4096, W11T, HH, H4);
    transpose_cast<<<dim3(32, 128), tb, 0, stream>>>(W2, W20T, H4, HH);
    transpose_cast<<<dim3(32, 128), tb, 0, stream>>>(W2 + 4096 * 1024, W21T, H4, HH);
    cast_bf16<<<(VV * HH + 255) / 256, 256, 0, stream>>>(emb, embB, VV * HH);
    gather_ln<<<dim3(TT, BB), 256, 0, stream>>>(x, emb, ln_g, ln_b, xe, xn0);

    // Phase A GEMMs (parallel precompute)
    gemm_bt<0><<<dim3(32, 16), 256, 0, stream>>>(xn0, WlxT0, pre_z0, nullptr, bl, 2048, 4096, 1024);
    gemm_bt<1><<<dim3(32, 16), 256, 0, stream>>>(xn0, W10T, nullptr, U0, b1, 2048, 4096, 1024);
    gemm_bt<0><<<dim3(8, 16), 256, 0, stream>>>(U0, W20T, ff0, nullptr, b2, 2048, 1024, 4096);

    // zero rings + progress
    zero_buf<<<1433, 256, 0, stream>>>((float*)R, 366624);

    // Phase B: 3-stage pipelined recurrence (L0 chain | zx1 | L1 chain)
    lstm_pipe<<<192, 512, 0, stream>>>(WlhT0, Wo0T, WlxT1, WlhT1, pre_z0, xe, ff0,
                                       ln_g, ln_b, bl, bo, y0_all, xn1, H1bf, R);

    // Phase C: deferred layer-1 output + logits
    gemm_bt<1><<<dim3(32, 16), 256, 0, stream>>>(xn1, W11T, nullptr, U1, b1 + 4096, 2048, 4096, 1024);
    p1_add<<<8192, 256, 0, stream>>>(y0_all, xe, b2 + 1024, bo + 1024);
    gemm_bt<2><<<dim3(8, 16), 256, 0, stream>>>(U1, W21T, y0_all, nullptr, nullptr, 2048, 1024, 4096);
    gemm_bt<2><<<dim3(8, 16), 256, 0, stream>>>(H1bf, Wo1T, y0_all, nullptr, nullptr, 2048, 1024, 1024);
    p2_cast<<<8192, 256, 0, stream>>>(y0_all, Y1bf);
    gemm_bt<3><<<dim3(250, 16), 256, 0, stream>>>(Y1bf, embB, out, nullptr, nullptr, 2048, 32000, 1024);
}

// Round 12
// 3693.382 us; speedup vs baseline: 2.9894x; 1.0916x over previous
//
#include <hip/hip_runtime.h>

typedef unsigned short u16;
typedef short bf16x8 __attribute__((ext_vector_type(8)));
typedef unsigned short ushort8 __attribute__((ext_vector_type(8)));
typedef unsigned short us4 __attribute__((ext_vector_type(4)));
typedef unsigned u32x4 __attribute__((ext_vector_type(4)));
typedef float fx4 __attribute__((ext_vector_type(4)));

#define DEVI __device__ __forceinline__

enum { BB = 4, TT = 512, HH = 1024, VV = 32000, H4 = 4096 };
enum { WSTR = 1032 };  // u16 row stride for LDS weight/stage arrays

DEVI u16 f2bf(float f) {
    union { float f; unsigned u; } x; x.f = f;
    unsigned r = x.u + 0x7fff + ((x.u >> 16) & 1);
    return (u16)(r >> 16);
}
DEVI float bf2f(u16 u) {
    union { unsigned u; float f; } x; x.u = ((unsigned)u) << 16;
    return x.f;
}
DEVI float sigm(float x) { return 1.f / (1.f + __expf(-x)); }

DEVI unsigned ald_u32(const unsigned* p) { return __hip_atomic_load(p, __ATOMIC_RELAXED, __HIP_MEMORY_SCOPE_AGENT); }
DEVI void ast_u32(unsigned* p, unsigned v) { __hip_atomic_store(p, v, __ATOMIC_RELAXED, __HIP_MEMORY_SCOPE_AGENT); }

DEVI void ld4cc(const unsigned* p, u32x4* out) {
    asm volatile("global_load_dwordx4 %0, %1, off sc0 sc1" : "=v"(*out) : "v"(p));
}

// poll a 4096-word tagged region ([4][1024] b-major) into LDS st[4][WSTR] (bf16 payloads)
DEVI void poll4096(const unsigned* base, unsigned want, u16* st, int tid) {
    const unsigned* p0 = base + tid * 8;
    const unsigned* p1 = p0 + 4;
    u32x4 v0, v1;
    ld4cc(p0, &v0); ld4cc(p1, &v1);
    asm volatile("s_waitcnt vmcnt(0)" ::: "memory");
    __builtin_amdgcn_sched_barrier(0);
    for (;;) {
        bool o0 = ((v0[0]>>16)==want)&((v0[1]>>16)==want)&((v0[2]>>16)==want)&((v0[3]>>16)==want);
        bool o1 = ((v1[0]>>16)==want)&((v1[1]>>16)==want)&((v1[2]>>16)==want)&((v1[3]>>16)==want);
        if (o0 & o1) break;
        __builtin_amdgcn_s_sleep(4);
        if (!o0) ld4cc(p0, &v0);
        if (!o1) ld4cc(p1, &v1);
        asm volatile("s_waitcnt vmcnt(0)" ::: "memory");
        __builtin_amdgcn_sched_barrier(0);
    }
    int wi = tid * 8;
    u16* d = st + (wi >> 10) * WSTR + (wi & 1023);
    *(us4*)d       = (us4){(u16)v0[0], (u16)v0[1], (u16)v0[2], (u16)v0[3]};
    *(us4*)(d + 4) = (us4){(u16)v1[0], (u16)v1[1], (u16)v1[2], (u16)v1[3]};
}

DEVI unsigned poll_word(const unsigned* p, unsigned want) {
    unsigned v = ald_u32(p);
    while ((v >> 16) != want) { __builtin_amdgcn_s_sleep(2); v = ald_u32(p); }
    return v & 0xFFFFu;
}

// 64-row gate MFMA: D[64 rows][4 cols] = W(LDS) @ h(LDS bf16). 8 waves: wave wv
// handles rowtile wv&3, K-half wv>>2. Partials to fb[kh*256 + lr*4 + col].
DEVI void gates64(const u16* wl, const u16* st, float* fb, int tid) {
    int lane = tid & 63, wv = tid >> 6;
    int rt = wv & 3, kh = wv >> 2;
    fx4 acc = {0.f, 0.f, 0.f, 0.f};
    int aoff = (rt * 16 + (lane & 15)) * WSTR + (lane >> 4) * 8;
    int boff = (lane & 3) * WSTR + (lane >> 4) * 8;
#pragma unroll
    for (int kt = 0; kt < 16; kt++) {
        int k0 = (kh * 16 + kt) * 32;
        bf16x8 a = *(const bf16x8*)(wl + aoff + k0);
        bf16x8 b = *(const bf16x8*)(st + boff + k0);
        acc = __builtin_amdgcn_mfma_f32_16x16x32_bf16(a, b, acc, 0, 0, 0);
    }
    int col = lane & 15;
    if (col < 4) {
        int r0 = rt * 16 + (lane >> 4) * 4;
#pragma unroll
        for (int ri = 0; ri < 4; ri++) fb[kh * 256 + (r0 + ri) * 4 + col] = acc[ri];
    }
}

// ---------------- transpose + cast: src [R][C] f32 -> dst [C][R] bf16 ----------------
__global__ void transpose_cast(const float* __restrict__ src, u16* __restrict__ dst, int R, int C) {
    __shared__ float tile[32][33];
    int c0 = blockIdx.x * 32, r0 = blockIdx.y * 32;
    int x = threadIdx.x, y = threadIdx.y;
#pragma unroll
    for (int i = 0; i < 32; i += 8) tile[y + i][x] = src[(size_t)(r0 + y + i) * C + c0 + x];
    __syncthreads();
#pragma unroll
    for (int i = 0; i < 32; i += 8) dst[(size_t)(c0 + y + i) * R + r0 + x] = f2bf(tile[x][y + i]);
}

__global__ void cast_bf16(const float* __restrict__ src, u16* __restrict__ dst, int n) {
    int i = blockIdx.x * 256 + threadIdx.x;
    if (i < n) dst[i] = f2bf(src[i]);
}

__global__ void zero_buf(float* p, int n) {
    int i = blockIdx.x * 256 + threadIdx.x;
    if (i < n) p[i] = 0.f;
}

// ---------------- gather + layernorm (layer 0 input) ----------------
__global__ __launch_bounds__(256) void gather_ln(const int* __restrict__ x, const float* __restrict__ emb,
                                                 const float* __restrict__ g, const float* __restrict__ b,
                                                 float* __restrict__ xe, u16* __restrict__ xn0) {
    int t = blockIdx.x, bb = blockIdx.y;
    int row = x[bb * TT + t];
    const float* e = emb + (size_t)row * HH;
    float v[4]; float s = 0.f, s2 = 0.f;
#pragma unroll
    for (int p = 0; p < 4; p++) { v[p] = e[p * 256 + threadIdx.x]; s += v[p]; s2 += v[p] * v[p]; }
    __shared__ float ls[4], ls2[4];
    for (int off = 32; off; off >>= 1) { s += __shfl_xor(s, off); s2 += __shfl_xor(s2, off); }
    int w = threadIdx.x >> 6, lane = threadIdx.x & 63;
    if (lane == 0) { ls[w] = s; ls2[w] = s2; }
    __syncthreads();
    s = ls[0] + ls[1] + ls[2] + ls[3];
    s2 = ls2[0] + ls2[1] + ls2[2] + ls2[3];
    float mu = s * (1.f / HH);
    float var = s2 * (1.f / HH) - mu * mu;
    float rs = rsqrtf(var + 1e-6f);
    size_t base = ((size_t)t * BB + bb) * HH;
#pragma unroll
    for (int p = 0; p < 4; p++) {
        int j = p * 256 + threadIdx.x;
        xe[base + j] = v[p];
        xn0[base + j] = f2bf((v[p] - mu) * rs * g[j] + b[j]);
    }
}

// ---------------- MFMA GEMM: C[M,N] = A[M,K](bf16) * Bt[N,K](bf16)^T ----------------
template <int MODE>
__global__ __launch_bounds__(256) void gemm_bt(const u16* __restrict__ A, const u16* __restrict__ Bt,
                                               float* __restrict__ Cf, u16* __restrict__ Cb,
                                               const float* __restrict__ bias, int M, int N, int K) {
    __shared__ u16 ldsA[128 * 40];
    __shared__ u16 ldsB[128 * 40];
    const int tid = threadIdx.x;
    const int m0 = blockIdx.y * 128, n0 = blockIdx.x * 128;
    const int lane = tid & 63, wid = tid >> 6;
    const int wr = wid >> 1, wc = wid & 1;
    const int l15 = lane & 15, lk = (lane >> 4) * 8;
    fx4 acc[4][4];
#pragma unroll
    for (int a = 0; a < 4; a++)
#pragma unroll
        for (int b = 0; b < 4; b++) { fx4 z = {0.f, 0.f, 0.f, 0.f}; acc[a][b] = z; }

    const int arow = tid >> 2, acol = (tid & 3) * 8;
    for (int k0 = 0; k0 < K; k0 += 32) {
#pragma unroll
        for (int p = 0; p < 2; p++) {
            int r = arow + p * 64;
            ushort8 va = *(const ushort8*)(A + (size_t)(m0 + r) * K + k0 + acol);
            *(ushort8*)&ldsA[r * 40 + acol] = va;
            ushort8 vb = *(const ushort8*)(Bt + (size_t)(n0 + r) * K + k0 + acol);
            *(ushort8*)&ldsB[r * 40 + acol] = vb;
        }
        __syncthreads();
        bf16x8 af[4], bfr[4];
#pragma unroll
        for (int mi = 0; mi < 4; mi++) af[mi] = *(const bf16x8*)&ldsA[(wr * 64 + mi * 16 + l15) * 40 + lk];
#pragma unroll
        for (int ni = 0; ni < 4; ni++) bfr[ni] = *(const bf16x8*)&ldsB[(wc * 64 + ni * 16 + l15) * 40 + lk];
#pragma unroll
        for (int mi = 0; mi < 4; mi++)
#pragma unroll
            for (int ni = 0; ni < 4; ni++)
                acc[mi][ni] = __builtin_amdgcn_mfma_f32_16x16x32_bf16(af[mi], bfr[ni], acc[mi][ni], 0, 0, 0);
        __syncthreads();
    }
#pragma unroll
    for (int mi = 0; mi < 4; mi++) {
#pragma unroll
        for (int ni = 0; ni < 4; ni++) {
#pragma unroll
            for (int r = 0; r < 4; r++) {
                int gr = m0 + wr * 64 + mi * 16 + (lane >> 4) * 4 + r;
                int gc = n0 + wc * 64 + ni * 16 + l15;
                float v = acc[mi][ni][r];
                if (MODE == 0) {
                    Cf[(size_t)gr * N + gc] = v + bias[gc];
                } else if (MODE == 1) {
                    float u = v + bias[gc];
                    Cb[(size_t)gr * N + gc] = f2bf(u > 0.f ? u : 0.f);
                } else if (MODE == 2) {
                    Cf[(size_t)gr * N + gc] += v;
                } else {
                    int b = gr & 3, t = gr >> 2;
                    Cf[((size_t)b * TT + t) * VV + gc] = v;
                }
            }
        }
    }
}

// ---------------- Phase B: 4-stage pipelined dataflow ----------------
// R (u32): RH0[8][4096] | RH1[4][4096] | RPART[4][1024] | RXN[16][4096] | RZX[16][16384]
//          | PROGY[64*32] | PROGZX[64*32] | PROGL1
// Roles: 0-63 L0 chain (gates only) | 64-127 Y0/LN | 128-191 zx1 | 192-255 L1 chain.
__global__ __launch_bounds__(512, 1) void lstm_pipe(
    const u16* __restrict__ Wh0T, const u16* __restrict__ Wo0T,
    const u16* __restrict__ Wx1T, const u16* __restrict__ Wh1T,
    const float* __restrict__ pz_all, const float* __restrict__ xe, const float* __restrict__ ff0,
    const float* __restrict__ lng, const float* __restrict__ lnb,
    const float* __restrict__ bl, const float* __restrict__ bo,
    float* __restrict__ y0_all, u16* __restrict__ xn1, u16* __restrict__ H1bf,
    unsigned* __restrict__ R) {
    __shared__ u16 wlds[64 * WSTR];   // 129 KB weights
    __shared__ u16 stg[4 * WSTR];     // 8.1 KB staged vector (bf16)
    __shared__ float fb[1664];

    const int bid = blockIdx.x;
    const int tid = threadIdx.x;

    unsigned* RH0 = R;
    unsigned* RH1 = R + 32768;
    unsigned* RPART = R + 49152;
    unsigned* RXN = R + 53248;
    unsigned* RZX = R + 118784;
    unsigned* PROGY = R + 380928;
    unsigned* PROGZX = R + 382976;
    unsigned* PROGL1 = R + 385024;

    if (bid < 64) {
        // ================= L0 chain (gates only) =================
        const int w = bid;
        {
            int row = tid >> 3, kc = tid & 7;
            int gr = (row >> 4) * 1024 + w * 16 + (row & 15);
            const uint4* s = (const uint4*)(Wh0T + (size_t)gr * 1024 + kc * 128);
            uint4* d = (uint4*)(wlds + row * WSTR + kc * 128);
#pragma unroll
            for (int i = 0; i < 16; i++) d[i] = s[i];
        }
        if (tid < 64) fb[1024 + tid] = 0.f;   // c-state
        __syncthreads();

        for (int s = 0; s < TT; s++) {
            if ((s & 3) == 0 && tid < 64) {   // ring-8 guard vs Y0 lag
                for (;;) {
                    unsigned p = ald_u32(PROGY + tid * 32);
#pragma unroll
                    for (int off = 1; off < 64; off <<= 1) {
                        unsigned o = (unsigned)__shfl_xor((int)p, off);
                        p = p < o ? p : o;
                    }
                    if ((int)p >= s - 4) break;
                    __builtin_amdgcn_s_sleep(8);
                }
            }
            float pzv[4] = {0.f, 0.f, 0.f, 0.f};
            if (tid < 64) {
                int x = tid >> 2, b = tid & 3;
#pragma unroll
                for (int g = 0; g < 4; g++)
                    pzv[g] = pz_all[((size_t)s * 4 + b) * 4096 + g * 1024 + w * 16 + x];
            }
            poll4096(RH0 + ((s + 7) & 7) * 4096, (unsigned)s, stg, tid);
            __syncthreads();   // b1: stg ready
            float* gbuf = fb + (s & 1) * 512;
            gates64(wlds, stg, gbuf, tid);
            __syncthreads();   // b2: gbuf ready
            if (tid < 64) {
                int x = tid >> 2, b = tid & 3;
                float z0 = gbuf[(0*16+x)*4+b] + gbuf[256+(0*16+x)*4+b] + pzv[0];
                float z1 = gbuf[(1*16+x)*4+b] + gbuf[256+(1*16+x)*4+b] + pzv[1];
                float z2 = gbuf[(2*16+x)*4+b] + gbuf[256+(2*16+x)*4+b] + pzv[2];
                float z3 = gbuf[(3*16+x)*4+b] + gbuf[256+(3*16+x)*4+b] + pzv[3];
                float ig = sigm(z0), fg = sigm(z1), og = sigm(z2), gg = tanhf(z3);
                float c = fg * fb[1024 + tid] + ig * gg;
                fb[1024 + tid] = c;
                float h = og * tanhf(c);
                ast_u32(&RH0[(s & 7) * 4096 + b * 1024 + w * 16 + x],
                        ((unsigned)(s + 1) << 16) | f2bf(h));
            }
            // no 3rd barrier: stg free after b2; gbuf double-buffered; c-state tid<64 only
        }
    } else if (bid < 128) {
        // ================= Y0 / LN stage =================
        const int wy = bid - 64;
        {
            int row = tid >> 5, kc = tid & 31;   // 16 rows x 32 chunks(64B)
            const uint4* s = (const uint4*)(Wo0T + (size_t)(wy * 16 + row) * 1024 + kc * 32);
            uint4* d = (uint4*)(wlds + row * WSTR + kc * 32);
            d[0] = s[0]; d[1] = s[1]; d[2] = s[2]; d[3] = s[3];
        }
        float lgR = 0.f, lbR = 0.f, boR = 0.f;
        if (tid < 64) {
            int x = tid >> 2;
            lgR = lng[1024 + wy * 16 + x];
            lbR = lnb[1024 + wy * 16 + x];
            boR = bo[wy * 16 + x];
        }
        __syncthreads();

        for (int t = 0; t <= TT; t++) {
            const bool doDot = (t < TT);
            const bool doLN = (t >= 1);
            if ((t & 7) == 0 && tid < 64) {   // RXN ring-16 guard vs zx lag
                for (;;) {
                    unsigned p = ald_u32(PROGZX + tid * 32);
#pragma unroll
                    for (int off = 1; off < 64; off <<= 1) {
                        unsigned o = (unsigned)__shfl_xor((int)p, off);
                        p = p < o ? p : o;
                    }
                    if ((int)p >= t - 8) break;
                    __builtin_amdgcn_s_sleep(8);
                }
            }
            float xev = 0.f, ffv = 0.f;
            if (doDot && tid < 64) {
                int x = tid >> 2, b = tid & 3;
                size_t base = ((size_t)t * 4 + b) * 1024 + wy * 16 + x;
                xev = xe[base]; ffv = ff0[base];
            }
            if (doDot) poll4096(RH0 + (t & 7) * 4096, (unsigned)(t + 1), stg, tid);
            __syncthreads();   // b1: stg (h0[t]) ready
            if (doDot && tid == 0) ast_u32(PROGY + wy * 32, (unsigned)(t + 1));
            if (doDot) {
                int out = tid >> 3, c = tid & 7;
                const u16* wrow = wlds + (out >> 2) * WSTR + c * 128;
                const u16* hrow = stg + (out & 3) * WSTR + c * 128;
                float acc = 0.f;
#pragma unroll
                for (int m = 0; m < 16; m++) {
                    ushort8 w8 = *(const ushort8*)(wrow + m * 8);
                    ushort8 h8 = *(const ushort8*)(hrow + m * 8);
#pragma unroll
                    for (int q = 0; q < 8; q++) acc += bf2f(w8[q]) * bf2f(h8[q]);
                }
                acc += __shfl_xor(acc, 1); acc += __shfl_xor(acc, 2); acc += __shfl_xor(acc, 4);
                if (c == 0) fb[512 + out] = acc;
            }
            if (doLN) {   // partial sums of y0[t-1] (published last step; ~ready)
                const unsigned* p = RPART + ((t - 1) & 3) * 1024 + tid * 2;
                unsigned hi = poll_word(p, (unsigned)t);
                unsigned lo = poll_word(p + 1, (unsigned)t);
                union { unsigned u; float f; } cv; cv.u = (hi << 16) | lo;
                fb[tid] = cv.f;
            }
            __syncthreads();   // b2: fbD + fbP ready
            if (doLN && tid < 8) {
                int b = tid & 3, kind = tid >> 2;
                float S = 0.f;
                for (int i = 0; i < 64; i++) S += fb[i * 8 + b * 2 + kind];
                fb[704 + kind * 4 + b] = S;
            }
            if (doDot && tid < 64) {
                int x = tid >> 2, b = tid & 3;
                float y = fb[512 + tid] + xev + ffv + boR;
                y0_all[((size_t)t * 4 + b) * 1024 + wy * 16 + x] = y;
                fb[576 + (t & 1) * 64 + tid] = y;
                float sv = y, sq = y * y;
#pragma unroll
                for (int off = 4; off < 64; off <<= 1) { sv += __shfl_xor(sv, off); sq += __shfl_xor(sq, off); }
                if (tid < 4) {
                    unsigned tg = (unsigned)(t + 1) << 16;
                    unsigned* pb = RPART + (t & 3) * 1024 + wy * 16 + tid * 4;
                    union { float f; unsigned u; } c1, c2; c1.f = sv; c2.f = sq;
                    ast_u32(pb + 0, tg | (c1.u >> 16));
                    ast_u32(pb + 1, tg | (c1.u & 0xFFFFu));
                    ast_u32(pb + 2, tg | (c2.u >> 16));
                    ast_u32(pb + 3, tg | (c2.u & 0xFFFFu));
                }
            }
            __syncthreads();   // b3: fbS ready
            if (doLN && tid < 64) {
                int x = tid >> 2, b = tid & 3;
                int u = t - 1;
                float mu = fb[704 + b] * (1.f / 1024.f);
                float rs = rsqrtf(fb[708 + b] * (1.f / 1024.f) - mu * mu + 1e-6f);
                float yv = fb[576 + (u & 1) * 64 + tid];
                float xnv = (yv - mu) * rs * lgR + lbR;
                u16 xb = f2bf(xnv);
                xn1[(size_t)u * 4096 + b * 1024 + wy * 16 + x] = xb;
                ast_u32(&RXN[(u & 15) * 4096 + b * 1024 + wy * 16 + x],
                        ((unsigned)(u + 1) << 16) | xb);
            }
        }
    } else if (bid < 192) {
        // ================= zx1 group =================
        const int wz = bid - 128;
        {
            int row = tid >> 3, kc = tid & 7;
            int gr = (row >> 4) * 1024 + wz * 16 + (row & 15);
            const uint4* s = (const uint4*)(Wx1T + (size_t)gr * 1024 + kc * 128);
            uint4* d = (uint4*)(wlds + row * WSTR + kc * 128);
#pragma unroll
            for (int i = 0; i < 16; i++) d[i] = s[i];
        }
        if (tid < 64) fb[1536 + tid] = bl[4096 + (tid >> 4) * 1024 + wz * 16 + (tid & 15)];
        __syncthreads();

        for (int t = 0; t < TT; t++) {
            if ((t & 7) == 0 && tid == 0) {
                while ((int)ald_u32(PROGL1) < t - 6) __builtin_amdgcn_s_sleep(8);
            }
            poll4096(RXN + (t & 15) * 4096, (unsigned)(t + 1), stg, tid);
            __syncthreads();
            gates64(wlds, stg, fb, tid);
            __syncthreads();
            if (tid == 0) ast_u32(PROGZX + wz * 32, (unsigned)(t + 1));
            if (tid < 256) {
                int lr = tid >> 2, b = tid & 3;
                float v = fb[lr * 4 + b] + fb[256 + lr * 4 + b] + fb[1536 + lr];
                ast_u32(&RZX[(t & 15) * 16384 + wz * 256 + tid],
                        ((unsigned)(t + 1) << 16) | f2bf(v));
            }
            __syncthreads();
        }
    } else {
        // ================= L1 chain =================
        const int w1 = bid - 192;
        {
            int row = tid >> 3, kc = tid & 7;
            int gr = (row >> 4) * 1024 + w1 * 16 + (row & 15);
            const uint4* s = (const uint4*)(Wh1T + (size_t)gr * 1024 + kc * 128);
            uint4* d = (uint4*)(wlds + row * WSTR + kc * 128);
#pragma unroll
            for (int i = 0; i < 16; i++) d[i] = s[i];
        }
        if (tid < 64) fb[1600 + tid] = 0.f;   // c-state
        __syncthreads();

        for (int v = 0; v < TT; v++) {
            poll4096(RH1 + ((v + 3) & 3) * 4096, (unsigned)v, stg, tid);
            if (tid < 256) {
                const unsigned* p = RZX + (v & 15) * 16384 + w1 * 256 + tid;
                fb[1024 + (v & 1) * 256 + tid] = bf2f((u16)poll_word(p, (unsigned)(v + 1)));
            }
            __syncthreads();   // b1
            if (bid == 192 && tid == 0) ast_u32(PROGL1, (unsigned)(v + 1));
            float* gbuf = fb + (v & 1) * 512;
            gates64(wlds, stg, gbuf, tid);
            __syncthreads();   // b2
            if (tid < 64) {
                int x = tid >> 2, b = tid & 3;
                const float* zb = fb + 1024 + (v & 1) * 256;
                float z0 = gbuf[(0*16+x)*4+b] + gbuf[256+(0*16+x)*4+b] + zb[(0*16+x)*4+b];
                float z1 = gbuf[(1*16+x)*4+b] + gbuf[256+(1*16+x)*4+b] + zb[(1*16+x)*4+b];
                float z2 = gbuf[(2*16+x)*4+b] + gbuf[256+(2*16+x)*4+b] + zb[(2*16+x)*4+b];
                float z3 = gbuf[(3*16+x)*4+b] + gbuf[256+(3*16+x)*4+b] + zb[(3*16+x)*4+b];
                float ig = sigm(z0), fg = sigm(z1), og = sigm(z2), gg = tanhf(z3);
                float c = fg * fb[1600 + tid] + ig * gg;
                fb[1600 + tid] = c;
                float h = og * tanhf(c);
                u16 hb = f2bf(h);
                H1bf[(size_t)v * 4096 + b * 1024 + w1 * 16 + x] = hb;
                ast_u32(&RH1[(v & 3) * 4096 + b * 1024 + w1 * 16 + x],
                        ((unsigned)(v + 1) << 16) | hb);
            }
        }
    }
}

// ---------------- post-loop elementwise ----------------
__global__ void p1_add(float* __restrict__ y, const float* __restrict__ xe,
                       const float* __restrict__ b2_1, const float* __restrict__ bo_1) {
    int idx = blockIdx.x * 256 + threadIdx.x;
    int j = idx & (HH - 1);
    y[idx] += xe[idx] + b2_1[j] + bo_1[j];
}

__global__ void p2_cast(const float* __restrict__ y, u16* __restrict__ o) {
    int idx = blockIdx.x * 256 + threadIdx.x;
    o[idx] = f2bf(y[idx]);
}

// ---------------- host ----------------
extern "C" void kernel_launch(void* const* d_in, const int* in_sizes, int n_in,
                              void* d_out, int out_size, void* d_ws, size_t ws_size,
                              hipStream_t stream) {
    const int* x = (const int*)d_in[0];
    const float* emb = (const float*)d_in[1];
    const float* ln_g = (const float*)d_in[2];
    const float* ln_b = (const float*)d_in[3];
    const float* Wl = (const float*)d_in[4];
    const float* bl = (const float*)d_in[5];
    const float* Wo = (const float*)d_in[6];
    const float* bo = (const float*)d_in[7];
    const float* W1 = (const float*)d_in[8];
    const float* b1 = (const float*)d_in[9];
    const float* W2 = (const float*)d_in[10];
    const float* b2 = (const float*)d_in[11];
    float* out = (float*)d_out;

    char* wp = (char*)d_ws;
    auto alloc = [&](size_t bytes) { void* p = wp; wp += (bytes + 255) & ~(size_t)255; return p; };
    const size_t MBT = (size_t)TT * BB;  // 2048 rows
    float* xe     = (float*)alloc(MBT * HH * 4);
    float* pre_z0 = (float*)alloc(MBT * H4 * 4);
    float* ff0    = (float*)alloc(MBT * HH * 4);
    float* y0_all = (float*)alloc(MBT * HH * 4);
    u16* xn0      = (u16*)alloc(MBT * HH * 2);
    u16* xn1      = (u16*)alloc(MBT * HH * 2);
    u16* U0       = (u16*)alloc(MBT * H4 * 2);
    u16* U1       = (u16*)alloc(MBT * H4 * 2);
    u16* H1bf     = (u16*)alloc(MBT * HH * 2);
    u16* Y1bf     = (u16*)alloc(MBT * HH * 2);
    // dataflow rings: RH0 32768 | RH1 16384 | RPART 4096 | RXN 65536 | RZX 262144 | prog 4128
    unsigned* R   = (unsigned*)alloc(385056 * 4);
    u16* WlxT0 = (u16*)alloc((size_t)H4 * HH * 2);
    u16* WlhT0 = (u16*)alloc((size_t)H4 * HH * 2);
    u16* WlxT1 = (u16*)alloc((size_t)H4 * HH * 2);
    u16* WlhT1 = (u16*)alloc((size_t)H4 * HH * 2);
    u16* Wo0T  = (u16*)alloc((size_t)HH * HH * 2);
    u16* Wo1T  = (u16*)alloc((size_t)HH * HH * 2);
    u16* W10T  = (u16*)alloc((size_t)H4 * HH * 2);
    u16* W11T  = (u16*)alloc((size_t)H4 * HH * 2);
    u16* W20T  = (u16*)alloc((size_t)HH * H4 * 2);
    u16* W21T  = (u16*)alloc((size_t)HH * H4 * 2);
    u16* embB  = (u16*)alloc((size_t)VV * HH * 2);

    dim3 tb(32, 8);
    // Wl: [L][2H][4H]; rows 0..H-1 = x-part, H..2H-1 = h-part
    transpose_cast<<<dim3(128, 32), tb, 0, stream>>>(Wl, WlxT0, HH, H4);
    transpose_cast<<<dim3(128, 32), tb, 0, stream>>>(Wl + 1024 * 4096, WlhT0, HH, H4);
    transpose_cast<<<dim3(128, 32), tb, 0, stream>>>(Wl + 2048 * 4096, WlxT1, HH, H4);
    transpose_cast<<<dim3(128, 32), tb, 0, stream>>>(Wl + 3072 * 4096, WlhT1, HH, H4);
    transpose_cast<<<dim3(32, 32), tb, 0, stream>>>(Wo, Wo0T, HH, HH);
    transpose_cast<<<dim3(32, 32), tb, 0, stream>>>(Wo + 1024 * 1024, Wo1T, HH, HH);
    transpose_cast<<<dim3(128, 32), tb, 0, stream>>>(W1, W10T, HH, H4);
    transpose_cast<<<dim3(128, 32), tb, 0, stream>>>(W1 + 1024 * 4096, W11T, HH, H4);
    transpose_cast<<<dim3(32, 128), tb, 0, stream>>>(W2, W20T, H4, HH);
    transpose_cast<<<dim3(32, 128), tb, 0, stream>>>(W2 + 4096 * 1024, W21T, H4, HH);
    cast_bf16<<<(VV * HH + 255) / 256, 256, 0, stream>>>(emb, embB, VV * HH);
    gather_ln<<<dim3(TT, BB), 256, 0, stream>>>(x, emb, ln_g, ln_b, xe, xn0);

    // Phase A GEMMs (parallel precompute)
    gemm_bt<0><<<dim3(32, 16), 256, 0, stream>>>(xn0, WlxT0, pre_z0, nullptr, bl, 2048, 4096, 1024);
    gemm_bt<1><<<dim3(32, 16), 256, 0, stream>>>(xn0, W10T, nullptr, U0, b1, 2048, 4096, 1024);
    gemm_bt<0><<<dim3(8, 16), 256, 0, stream>>>(U0, W20T, ff0, nullptr, b2, 2048, 1024, 4096);

    // zero rings + progress
    zero_buf<<<1505, 256, 0, stream>>>((float*)R, 385056);

    // Phase B: 4-stage pipelined recurrence (L0 | Y0/LN | zx1 | L1)
    lstm_pipe<<<256, 512, 0, stream>>>(WlhT0, Wo0T, WlxT1, WlhT1, pre_z0, xe, ff0,
                                       ln_g, ln_b, bl, bo, y0_all, xn1, H1bf, R);

    // Phase C: deferred layer-1 output + logits
    gemm_bt<1><<<dim3(32, 16), 256, 0, stream>>>(xn1, W11T, nullptr, U1, b1 + 4096, 2048, 4096, 1024);
    p1_add<<<8192, 256, 0, stream>>>(y0_all, xe, b2 + 1024, bo + 1024);
    gemm_bt<2><<<dim3(8, 16), 256, 0, stream>>>(U1, W21T, y0_all, nullptr, nullptr, 2048, 1024, 4096);
    gemm_bt<2><<<dim3(8, 16), 256, 0, stream>>>(H1bf, Wo1T, y0_all, nullptr, nullptr, 2048, 1024, 1024);
    p2_cast<<<8192, 256, 0, stream>>>(y0_all, Y1bf);
    gemm_bt<3><<<dim3(250, 16), 256, 0, stream>>>(Y1bf, embB, out, nullptr, nullptr, 2048, 32000, 1024);
}

// Round 14
// 3640.710 us; speedup vs baseline: 3.0326x; 1.0145x over previous
//
#include <hip/hip_runtime.h>

typedef unsigned short u16;
typedef short bf16x8 __attribute__((ext_vector_type(8)));
typedef unsigned short ushort8 __attribute__((ext_vector_type(8)));
typedef unsigned short us4 __attribute__((ext_vector_type(4)));
typedef unsigned u32x4 __attribute__((ext_vector_type(4)));
typedef float fx4 __attribute__((ext_vector_type(4)));

#define DEVI __device__ __forceinline__

enum { BB = 4, TT = 512, HH = 1024, VV = 32000, H4 = 4096 };
enum { WSTR = 1032 };  // u16 row stride for LDS weight/stage arrays

DEVI u16 f2bf(float f) {
    union { float f; unsigned u; } x; x.f = f;
    unsigned r = x.u + 0x7fff + ((x.u >> 16) & 1);
    return (u16)(r >> 16);
}
DEVI float bf2f(u16 u) {
    union { unsigned u; float f; } x; x.u = ((unsigned)u) << 16;
    return x.f;
}
DEVI float sigm(float x) { return 1.f / (1.f + __expf(-x)); }
DEVI float tanh_f(float x) {   // overflow-safe fast tanh via expf
    float a = fabsf(x);
    float t = 1.f - 2.f / (__expf(2.f * a) + 1.f);
    return x < 0.f ? -t : t;
}

DEVI unsigned ald_u32(const unsigned* p) { return __hip_atomic_load(p, __ATOMIC_RELAXED, __HIP_MEMORY_SCOPE_AGENT); }
DEVI void ast_u32(unsigned* p, unsigned v) { __hip_atomic_store(p, v, __ATOMIC_RELAXED, __HIP_MEMORY_SCOPE_AGENT); }

DEVI void ld4cc(const unsigned* p, u32x4* out) {
    asm volatile("global_load_dwordx4 %0, %1, off sc0 sc1" : "=v"(*out) : "v"(p));
}

// ---- sentinel hop protocol (h rings) ----
// wave-0 poll of 64 per-producer sentinels; returns when all == want
template <int SLP>
DEVI void sent_poll(const unsigned* sbase, unsigned want, int lane) {
    const unsigned* p = sbase + lane;
    unsigned v = ald_u32(p);
    while (v != want) { __builtin_amdgcn_s_sleep(SLP); v = ald_u32(p); }
}
// all-thread payload fetch: 1 dwordx4 (8 bf16) -> stg
DEVI void data_fetch(const unsigned* dbase, u16* st, int tid) {
    u32x4 d;
    ld4cc(dbase + tid * 4, &d);
    asm volatile("s_waitcnt vmcnt(0)" ::: "memory");
    __builtin_amdgcn_sched_barrier(0);
    int wi = tid * 8;
    u16* dst = st + (wi >> 10) * WSTR + (wi & 1023);
    *(us4*)dst       = (us4){(u16)d[0], (u16)(d[0] >> 16), (u16)d[1], (u16)(d[1] >> 16)};
    *(us4*)(dst + 4) = (us4){(u16)d[2], (u16)(d[2] >> 16), (u16)d[3], (u16)(d[3] >> 16)};
}

// poll a 4096-word tagged region ([4][1024] b-major) into LDS st[4][WSTR] (bf16 payloads)
template <int SLP>
DEVI void poll4096(const unsigned* base, unsigned want, u16* st, int tid) {
    const unsigned* p0 = base + tid * 8;
    const unsigned* p1 = p0 + 4;
    u32x4 v0, v1;
    ld4cc(p0, &v0); ld4cc(p1, &v1);
    asm volatile("s_waitcnt vmcnt(0)" ::: "memory");
    __builtin_amdgcn_sched_barrier(0);
    for (;;) {
        bool o0 = ((v0[0]>>16)==want)&((v0[1]>>16)==want)&((v0[2]>>16)==want)&((v0[3]>>16)==want);
        bool o1 = ((v1[0]>>16)==want)&((v1[1]>>16)==want)&((v1[2]>>16)==want)&((v1[3]>>16)==want);
        if (o0 & o1) break;
        __builtin_amdgcn_s_sleep(SLP);
        if (!o0) ld4cc(p0, &v0);
        if (!o1) ld4cc(p1, &v1);
        asm volatile("s_waitcnt vmcnt(0)" ::: "memory");
        __builtin_amdgcn_sched_barrier(0);
    }
    int wi = tid * 8;
    u16* d = st + (wi >> 10) * WSTR + (wi & 1023);
    *(us4*)d       = (us4){(u16)v0[0], (u16)v0[1], (u16)v0[2], (u16)v0[3]};
    *(us4*)(d + 4) = (us4){(u16)v1[0], (u16)v1[1], (u16)v1[2], (u16)v1[3]};
}

DEVI unsigned poll_word(const unsigned* p, unsigned want) {
    unsigned v = ald_u32(p);
    while ((v >> 16) != want) { __builtin_amdgcn_s_sleep(2); v = ald_u32(p); }
    return v & 0xFFFFu;
}

// 64-row gate MFMA: D[64 rows][4 cols] = W(LDS) @ h(LDS bf16). 8 waves: wave wv
// handles rowtile wv&3, K-half wv>>2. Partials to fb[kh*256 + lr*4 + col].
DEVI void gates64(const u16* wl, const u16* st, float* fb, int tid) {
    int lane = tid & 63, wv = tid >> 6;
    int rt = wv & 3, kh = wv >> 2;
    fx4 acc = {0.f, 0.f, 0.f, 0.f};
    int aoff = (rt * 16 + (lane & 15)) * WSTR + (lane >> 4) * 8;
    int boff = (lane & 3) * WSTR + (lane >> 4) * 8;
#pragma unroll
    for (int kt = 0; kt < 16; kt++) {
        int k0 = (kh * 16 + kt) * 32;
        bf16x8 a = *(const bf16x8*)(wl + aoff + k0);
        bf16x8 b = *(const bf16x8*)(st + boff + k0);
        acc = __builtin_amdgcn_mfma_f32_16x16x32_bf16(a, b, acc, 0, 0, 0);
    }
    int col = lane & 15;
    if (col < 4) {
        int r0 = rt * 16 + (lane >> 4) * 4;
#pragma unroll
        for (int ri = 0; ri < 4; ri++) fb[kh * 256 + (r0 + ri) * 4 + col] = acc[ri];
    }
}

// ---------------- transpose + cast: src [R][C] f32 -> dst [C][R] bf16 ----------------
__global__ void transpose_cast(const float* __restrict__ src, u16* __restrict__ dst, int R, int C) {
    __shared__ float tile[32][33];
    int c0 = blockIdx.x * 32, r0 = blockIdx.y * 32;
    int x = threadIdx.x, y = threadIdx.y;
#pragma unroll
    for (int i = 0; i < 32; i += 8) tile[y + i][x] = src[(size_t)(r0 + y + i) * C + c0 + x];
    __syncthreads();
#pragma unroll
    for (int i = 0; i < 32; i += 8) dst[(size_t)(c0 + y + i) * R + r0 + x] = f2bf(tile[x][y + i]);
}

__global__ void cast_bf16(const float* __restrict__ src, u16* __restrict__ dst, int n) {
    int i = blockIdx.x * 256 + threadIdx.x;
    if (i < n) dst[i] = f2bf(src[i]);
}

__global__ void zero_buf(float* p, int n) {
    int i = blockIdx.x * 256 + threadIdx.x;
    if (i < n) p[i] = 0.f;
}

// ---------------- gather + layernorm (layer 0 input) ----------------
__global__ __launch_bounds__(256) void gather_ln(const int* __restrict__ x, const float* __restrict__ emb,
                                                 const float* __restrict__ g, const float* __restrict__ b,
                                                 float* __restrict__ xe, u16* __restrict__ xn0) {
    int t = blockIdx.x, bb = blockIdx.y;
    int row = x[bb * TT + t];
    const float* e = emb + (size_t)row * HH;
    float v[4]; float s = 0.f, s2 = 0.f;
#pragma unroll
    for (int p = 0; p < 4; p++) { v[p] = e[p * 256 + threadIdx.x]; s += v[p]; s2 += v[p] * v[p]; }
    __shared__ float ls[4], ls2[4];
    for (int off = 32; off; off >>= 1) { s += __shfl_xor(s, off); s2 += __shfl_xor(s2, off); }
    int w = threadIdx.x >> 6, lane = threadIdx.x & 63;
    if (lane == 0) { ls[w] = s; ls2[w] = s2; }
    __syncthreads();
    s = ls[0] + ls[1] + ls[2] + ls[3];
    s2 = ls2[0] + ls2[1] + ls2[2] + ls2[3];
    float mu = s * (1.f / HH);
    float var = s2 * (1.f / HH) - mu * mu;
    float rs = rsqrtf(var + 1e-6f);
    size_t base = ((size_t)t * BB + bb) * HH;
#pragma unroll
    for (int p = 0; p < 4; p++) {
        int j = p * 256 + threadIdx.x;
        xe[base + j] = v[p];
        xn0[base + j] = f2bf((v[p] - mu) * rs * g[j] + b[j]);
    }
}

// ---------------- MFMA GEMM: C[M,N] = A[M,K](bf16) * Bt[N,K](bf16)^T ----------------
template <int MODE>
__global__ __launch_bounds__(256) void gemm_bt(const u16* __restrict__ A, const u16* __restrict__ Bt,
                                               float* __restrict__ Cf, u16* __restrict__ Cb,
                                               const float* __restrict__ bias, int M, int N, int K) {
    __shared__ u16 ldsA[128 * 40];
    __shared__ u16 ldsB[128 * 40];
    const int tid = threadIdx.x;
    const int m0 = blockIdx.y * 128, n0 = blockIdx.x * 128;
    const int lane = tid & 63, wid = tid >> 6;
    const int wr = wid >> 1, wc = wid & 1;
    const int l15 = lane & 15, lk = (lane >> 4) * 8;
    fx4 acc[4][4];
#pragma unroll
    for (int a = 0; a < 4; a++)
#pragma unroll
        for (int b = 0; b < 4; b++) { fx4 z = {0.f, 0.f, 0.f, 0.f}; acc[a][b] = z; }

    const int arow = tid >> 2, acol = (tid & 3) * 8;
    for (int k0 = 0; k0 < K; k0 += 32) {
#pragma unroll
        for (int p = 0; p < 2; p++) {
            int r = arow + p * 64;
            ushort8 va = *(const ushort8*)(A + (size_t)(m0 + r) * K + k0 + acol);
            *(ushort8*)&ldsA[r * 40 + acol] = va;
            ushort8 vb = *(const ushort8*)(Bt + (size_t)(n0 + r) * K + k0 + acol);
            *(ushort8*)&ldsB[r * 40 + acol] = vb;
        }
        __syncthreads();
        bf16x8 af[4], bfr[4];
#pragma unroll
        for (int mi = 0; mi < 4; mi++) af[mi] = *(const bf16x8*)&ldsA[(wr * 64 + mi * 16 + l15) * 40 + lk];
#pragma unroll
        for (int ni = 0; ni < 4; ni++) bfr[ni] = *(const bf16x8*)&ldsB[(wc * 64 + ni * 16 + l15) * 40 + lk];
#pragma unroll
        for (int mi = 0; mi < 4; mi++)
#pragma unroll
            for (int ni = 0; ni < 4; ni++)
                acc[mi][ni] = __builtin_amdgcn_mfma_f32_16x16x32_bf16(af[mi], bfr[ni], acc[mi][ni], 0, 0, 0);
        __syncthreads();
    }
#pragma unroll
    for (int mi = 0; mi < 4; mi++) {
#pragma unroll
        for (int ni = 0; ni < 4; ni++) {
#pragma unroll
            for (int r = 0; r < 4; r++) {
                int gr = m0 + wr * 64 + mi * 16 + (lane >> 4) * 4 + r;
                int gc = n0 + wc * 64 + ni * 16 + l15;
                float v = acc[mi][ni][r];
                if (MODE == 0) {
                    Cf[(size_t)gr * N + gc] = v + bias[gc];
                } else if (MODE == 1) {
                    float u = v + bias[gc];
                    Cb[(size_t)gr * N + gc] = f2bf(u > 0.f ? u : 0.f);
                } else if (MODE == 2) {
                    Cf[(size_t)gr * N + gc] += v;
                } else {
                    int b = gr & 3, t = gr >> 2;
                    Cf[((size_t)b * TT + t) * VV + gc] = v;
                }
            }
        }
    }
}

// ---------------- Phase B: 4-stage pipelined dataflow, sentinel h-rings ----------------
// R (u32): RD0[16][2048] | RS0[16][64] | RD1[4][2048] | RS1[4][64] | RPART[4][1024]
//          | RXN[16][4096] | RZX[16][16384] | PROGY | PROGZX | PROGL1
// Roles: 0-63 L0 chain | 64-127 Y0/LN | 128-191 zx1 | 192-255 L1 chain.
__global__ __launch_bounds__(512, 1) void lstm_pipe(
    const u16* __restrict__ Wh0T, const u16* __restrict__ Wo0T,
    const u16* __restrict__ Wx1T, const u16* __restrict__ Wh1T,
    const float* __restrict__ pz_all, const float* __restrict__ xe, const float* __restrict__ ff0,
    const float* __restrict__ lng, const float* __restrict__ lnb,
    const float* __restrict__ bl, const float* __restrict__ bo,
    float* __restrict__ y0_all, u16* __restrict__ xn1, u16* __restrict__ H1bf,
    unsigned* __restrict__ R) {
    __shared__ u16 wlds[64 * WSTR];   // 129 KB weights
    __shared__ u16 stg[4 * WSTR];     // 8.1 KB staged vector (bf16)
    __shared__ float fb[1664];

    const int bid = blockIdx.x;
    const int tid = threadIdx.x;
    const int lane = tid & 63, wv = tid >> 6;

    unsigned* RD0 = R;
    unsigned* RS0 = R + 32768;
    unsigned* RD1 = R + 33792;
    unsigned* RS1 = R + 41984;
    unsigned* RPART = R + 42240;
    unsigned* RXN = R + 46336;
    unsigned* RZX = R + 111872;
    unsigned* PROGY = R + 374016;
    unsigned* PROGZX = R + 376064;
    unsigned* PROGL1 = R + 378112;

    if (bid < 64) {
        // ================= L0 chain (gates only, sentinel ring-16) =================
        const int w = bid;
        {
            int row = tid >> 3, kc = tid & 7;
            int gr = (row >> 4) * 1024 + w * 16 + (row & 15);
            const uint4* s = (const uint4*)(Wh0T + (size_t)gr * 1024 + kc * 128);
            uint4* d = (uint4*)(wlds + row * WSTR + kc * 128);
#pragma unroll
            for (int i = 0; i < 16; i++) d[i] = s[i];
        }
        if (tid < 64) fb[1024 + tid] = 0.f;   // c-state
        __syncthreads();

        for (int s = 0; s < TT; s++) {
            if ((s & 7) == 0 && tid < 64) {   // ring-16 guard vs Y0 lag (margin 8)
                for (;;) {
                    unsigned p = ald_u32(PROGY + tid * 32);
#pragma unroll
                    for (int off = 1; off < 64; off <<= 1) {
                        unsigned o = (unsigned)__shfl_xor((int)p, off);
                        p = p < o ? p : o;
                    }
                    if ((int)p >= s - 8) break;
                    __builtin_amdgcn_s_sleep(8);
                }
            }
            float pzv[4] = {0.f, 0.f, 0.f, 0.f};
            if (tid < 64) {
                int x = tid >> 2, b = tid & 3;
#pragma unroll
                for (int g = 0; g < 4; g++)
                    pzv[g] = pz_all[((size_t)s * 4 + b) * 4096 + g * 1024 + w * 16 + x];
            }
            if (wv == 0) sent_poll<1>(RS0 + ((s + 15) & 15) * 64, (unsigned)s, lane);
            __syncthreads();   // bS: h0[s-1] published
            data_fetch(RD0 + ((s + 15) & 15) * 2048, stg, tid);
            __syncthreads();   // b1: stg ready
            float* gbuf = fb + (s & 1) * 512;
            gates64(wlds, stg, gbuf, tid);
            __syncthreads();   // b2: gbuf ready
            if (tid < 64) {
                int x = tid >> 2, b = tid & 3;
                float z0 = gbuf[(0*16+x)*4+b] + gbuf[256+(0*16+x)*4+b] + pzv[0];
                float z1 = gbuf[(1*16+x)*4+b] + gbuf[256+(1*16+x)*4+b] + pzv[1];
                float z2 = gbuf[(2*16+x)*4+b] + gbuf[256+(2*16+x)*4+b] + pzv[2];
                float z3 = gbuf[(3*16+x)*4+b] + gbuf[256+(3*16+x)*4+b] + pzv[3];
                float ig = sigm(z0), fg = sigm(z1), og = sigm(z2), gg = tanh_f(z3);
                float c = fg * fb[1024 + tid] + ig * gg;
                fb[1024 + tid] = c;
                float h = og * tanh_f(c);
                float hn = __shfl(h, (tid + 4) & 63);
                if (((tid >> 2) & 1) == 0) {   // x even: store pair (x, x+1)
                    int x = tid >> 2, b = tid & 3;
                    unsigned word = (unsigned)f2bf(h) | ((unsigned)f2bf(hn) << 16);
                    ast_u32(&RD0[(s & 15) * 2048 + b * 512 + w * 8 + (x >> 1)], word);
                }
                asm volatile("s_waitcnt vmcnt(0)" ::: "memory");
                if (tid == 0) ast_u32(&RS0[(s & 15) * 64 + w], (unsigned)(s + 1));
            }
        }
    } else if (bid < 128) {
        // ================= Y0 / LN stage =================
        const int wy = bid - 64;
        {
            int row = tid >> 5, kc = tid & 31;
            const uint4* s = (const uint4*)(Wo0T + (size_t)(wy * 16 + row) * 1024 + kc * 32);
            uint4* d = (uint4*)(wlds + row * WSTR + kc * 32);
            d[0] = s[0]; d[1] = s[1]; d[2] = s[2]; d[3] = s[3];
        }
        float lgR = 0.f, lbR = 0.f, boR = 0.f;
        if (tid < 64) {
            int x = tid >> 2;
            lgR = lng[1024 + wy * 16 + x];
            lbR = lnb[1024 + wy * 16 + x];
            boR = bo[wy * 16 + x];
        }
        __syncthreads();

        for (int t = 0; t <= TT; t++) {
            const bool doDot = (t < TT);
            const bool doLN = (t >= 1);
            if ((t & 7) == 0 && tid < 64) {   // RXN ring-16 guard vs zx lag
                for (;;) {
                    unsigned p = ald_u32(PROGZX + tid * 32);
#pragma unroll
                    for (int off = 1; off < 64; off <<= 1) {
                        unsigned o = (unsigned)__shfl_xor((int)p, off);
                        p = p < o ? p : o;
                    }
                    if ((int)p >= t - 8) break;
                    __builtin_amdgcn_s_sleep(8);
                }
            }
            float xev = 0.f, ffv = 0.f;
            if (doDot && tid < 64) {
                int x = tid >> 2, b = tid & 3;
                size_t base = ((size_t)t * 4 + b) * 1024 + wy * 16 + x;
                xev = xe[base]; ffv = ff0[base];
            }
            if (doDot && wv == 0) sent_poll<4>(RS0 + (t & 15) * 64, (unsigned)(t + 1), lane);
            __syncthreads();   // bS
            if (doDot) data_fetch(RD0 + (t & 15) * 2048, stg, tid);
            if (doLN) {   // partial sums of y0[t-1]
                const unsigned* p = RPART + ((t - 1) & 3) * 1024 + tid * 2;
                unsigned hi = poll_word(p, (unsigned)t);
                unsigned lo = poll_word(p + 1, (unsigned)t);
                union { unsigned u; float f; } cv; cv.u = (hi << 16) | lo;
                fb[tid] = cv.f;
            }
            __syncthreads();   // b1: stg + fbP ready
            if (doDot && tid == 0) ast_u32(PROGY + wy * 32, (unsigned)(t + 1));
            if (doLN && tid < 8) {
                int b = tid & 3, kind = tid >> 2;
                float S = 0.f;
                for (int i = 0; i < 64; i++) S += fb[i * 8 + b * 2 + kind];
                fb[704 + kind * 4 + b] = S;
            }
            if (doDot) {
                int out = tid >> 3, c = tid & 7;
                const u16* wrow = wlds + (out >> 2) * WSTR + c * 128;
                const u16* hrow = stg + (out & 3) * WSTR + c * 128;
                float acc = 0.f;
#pragma unroll
                for (int m = 0; m < 16; m++) {
                    ushort8 w8 = *(const ushort8*)(wrow + m * 8);
                    ushort8 h8 = *(const ushort8*)(hrow + m * 8);
#pragma unroll
                    for (int q = 0; q < 8; q++) acc += bf2f(w8[q]) * bf2f(h8[q]);
                }
                acc += __shfl_xor(acc, 1); acc += __shfl_xor(acc, 2); acc += __shfl_xor(acc, 4);
                if (c == 0) fb[512 + out] = acc;
            }
            __syncthreads();   // b2
            if (doDot && tid < 64) {
                int x = tid >> 2, b = tid & 3;
                float y = fb[512 + tid] + xev + ffv + boR;
                y0_all[((size_t)t * 4 + b) * 1024 + wy * 16 + x] = y;
                fb[576 + (t & 1) * 64 + tid] = y;
                float sv = y, sq = y * y;
#pragma unroll
                for (int off = 4; off < 64; off <<= 1) { sv += __shfl_xor(sv, off); sq += __shfl_xor(sq, off); }
                if (tid < 4) {
                    unsigned tg = (unsigned)(t + 1) << 16;
                    unsigned* pb = RPART + (t & 3) * 1024 + wy * 16 + tid * 4;
                    union { float f; unsigned u; } c1, c2; c1.f = sv; c2.f = sq;
                    ast_u32(pb + 0, tg | (c1.u >> 16));
                    ast_u32(pb + 1, tg | (c1.u & 0xFFFFu));
                    ast_u32(pb + 2, tg | (c2.u >> 16));
                    ast_u32(pb + 3, tg | (c2.u & 0xFFFFu));
                }
            }
            __syncthreads();   // b3
            if (doLN && tid < 64) {
                int x = tid >> 2, b = tid & 3;
                int u = t - 1;
                float mu = fb[704 + b] * (1.f / 1024.f);
                float rs = rsqrtf(fb[708 + b] * (1.f / 1024.f) - mu * mu + 1e-6f);
                float yv = fb[576 + (u & 1) * 64 + tid];
                float xnv = (yv - mu) * rs * lgR + lbR;
                u16 xb = f2bf(xnv);
                xn1[(size_t)u * 4096 + b * 1024 + wy * 16 + x] = xb;
                ast_u32(&RXN[(u & 15) * 4096 + b * 1024 + wy * 16 + x],
                        ((unsigned)(u + 1) << 16) | xb);
            }
        }
    } else if (bid < 192) {
        // ================= zx1 group =================
        const int wz = bid - 128;
        {
            int row = tid >> 3, kc = tid & 7;
            int gr = (row >> 4) * 1024 + wz * 16 + (row & 15);
            const uint4* s = (const uint4*)(Wx1T + (size_t)gr * 1024 + kc * 128);
            uint4* d = (uint4*)(wlds + row * WSTR + kc * 128);
#pragma unroll
            for (int i = 0; i < 16; i++) d[i] = s[i];
        }
        if (tid < 64) fb[1536 + tid] = bl[4096 + (tid >> 4) * 1024 + wz * 16 + (tid & 15)];
        __syncthreads();

        for (int t = 0; t < TT; t++) {
            if ((t & 7) == 0 && tid == 0) {
                while ((int)ald_u32(PROGL1) < t - 6) __builtin_amdgcn_s_sleep(8);
            }
            poll4096<8>(RXN + (t & 15) * 4096, (unsigned)(t + 1), stg, tid);
            __syncthreads();
            gates64(wlds, stg, fb, tid);
            __syncthreads();
            if (tid == 0) ast_u32(PROGZX + wz * 32, (unsigned)(t + 1));
            if (tid < 256) {
                int lr = tid >> 2, b = tid & 3;
                float v = fb[lr * 4 + b] + fb[256 + lr * 4 + b] + fb[1536 + lr];
                ast_u32(&RZX[(t & 15) * 16384 + wz * 256 + tid],
                        ((unsigned)(t + 1) << 16) | f2bf(v));
            }
            __syncthreads();
        }
    } else {
        // ================= L1 chain (sentinel ring-4) =================
        const int w1 = bid - 192;
        {
            int row = tid >> 3, kc = tid & 7;
            int gr = (row >> 4) * 1024 + w1 * 16 + (row & 15);
            const uint4* s = (const uint4*)(Wh1T + (size_t)gr * 1024 + kc * 128);
            uint4* d = (uint4*)(wlds + row * WSTR + kc * 128);
#pragma unroll
            for (int i = 0; i < 16; i++) d[i] = s[i];
        }
        if (tid < 64) fb[1600 + tid] = 0.f;   // c-state
        __syncthreads();

        for (int v = 0; v < TT; v++) {
            if (tid < 256) {
                const unsigned* p = RZX + (v & 15) * 16384 + w1 * 256 + tid;
                fb[1024 + (v & 1) * 256 + tid] = bf2f((u16)poll_word(p, (unsigned)(v + 1)));
            }
            if (wv == 0) sent_poll<1>(RS1 + ((v + 3) & 3) * 64, (unsigned)v, lane);
            __syncthreads();   // bS
            data_fetch(RD1 + ((v + 3) & 3) * 2048, stg, tid);
            __syncthreads();   // b1
            if (bid == 192 && tid == 0) ast_u32(PROGL1, (unsigned)(v + 1));
            float* gbuf = fb + (v & 1) * 512;
            gates64(wlds, stg, gbuf, tid);
            __syncthreads();   // b2
            if (tid < 64) {
                int x = tid >> 2, b = tid & 3;
                const float* zb = fb + 1024 + (v & 1) * 256;
                float z0 = gbuf[(0*16+x)*4+b] + gbuf[256+(0*16+x)*4+b] + zb[(0*16+x)*4+b];
                float z1 = gbuf[(1*16+x)*4+b] + gbuf[256+(1*16+x)*4+b] + zb[(1*16+x)*4+b];
                float z2 = gbuf[(2*16+x)*4+b] + gbuf[256+(2*16+x)*4+b] + zb[(2*16+x)*4+b];
                float z3 = gbuf[(3*16+x)*4+b] + gbuf[256+(3*16+x)*4+b] + zb[(3*16+x)*4+b];
                float ig = sigm(z0), fg = sigm(z1), og = sigm(z2), gg = tanh_f(z3);
                float c = fg * fb[1600 + tid] + ig * gg;
                fb[1600 + tid] = c;
                float h = og * tanh_f(c);
                u16 hb = f2bf(h);
                H1bf[(size_t)v * 4096 + b * 1024 + w1 * 16 + x] = hb;
                float hn = __shfl(h, (tid + 4) & 63);
                if (((tid >> 2) & 1) == 0) {
                    unsigned word = (unsigned)hb | ((unsigned)f2bf(hn) << 16);
                    ast_u32(&RD1[(v & 3) * 2048 + b * 512 + w1 * 8 + ((tid >> 2) >> 1)], word);
                }
                asm volatile("s_waitcnt vmcnt(0)" ::: "memory");
                if (tid == 0) ast_u32(&RS1[(v & 3) * 64 + w1], (unsigned)(v + 1));
            }
        }
    }
}

// ---------------- post-loop elementwise ----------------
__global__ void p1_add(float* __restrict__ y, const float* __restrict__ xe,
                       const float* __restrict__ b2_1, const float* __restrict__ bo_1) {
    int idx = blockIdx.x * 256 + threadIdx.x;
    int j = idx & (HH - 1);
    y[idx] += xe[idx] + b2_1[j] + bo_1[j];
}

__global__ void p2_cast(const float* __restrict__ y, u16* __restrict__ o) {
    int idx = blockIdx.x * 256 + threadIdx.x;
    o[idx] = f2bf(y[idx]);
}

// ---------------- host ----------------
extern "C" void kernel_launch(void* const* d_in, const int* in_sizes, int n_in,
                              void* d_out, int out_size, void* d_ws, size_t ws_size,
                              hipStream_t stream) {
    const int* x = (const int*)d_in[0];
    const float* emb = (const float*)d_in[1];
    const float* ln_g = (const float*)d_in[2];
    const float* ln_b = (const float*)d_in[3];
    const float* Wl = (const float*)d_in[4];
    const float* bl = (const float*)d_in[5];
    const float* Wo = (const float*)d_in[6];
    const float* bo = (const float*)d_in[7];
    const float* W1 = (const float*)d_in[8];
    const float* b1 = (const float*)d_in[9];
    const float* W2 = (const float*)d_in[10];
    const float* b2 = (const float*)d_in[11];
    float* out = (float*)d_out;

    char* wp = (char*)d_ws;
    auto alloc = [&](size_t bytes) { void* p = wp; wp += (bytes + 255) & ~(size_t)255; return p; };
    const size_t MBT = (size_t)TT * BB;  // 2048 rows
    float* xe     = (float*)alloc(MBT * HH * 4);
    float* pre_z0 = (float*)alloc(MBT * H4 * 4);
    float* ff0    = (float*)alloc(MBT * HH * 4);
    float* y0_all = (float*)alloc(MBT * HH * 4);
    u16* xn0      = (u16*)alloc(MBT * HH * 2);
    u16* xn1      = (u16*)alloc(MBT * HH * 2);
    u16* U0       = (u16*)alloc(MBT * H4 * 2);
    u16* U1       = (u16*)alloc(MBT * H4 * 2);
    u16* H1bf     = (u16*)alloc(MBT * HH * 2);
    u16* Y1bf     = (u16*)alloc(MBT * HH * 2);
    // dataflow: RD0 32768 | RS0 1024 | RD1 8192 | RS1 256 | RPART 4096 | RXN 65536
    //           | RZX 262144 | PROGY 2048 | PROGZX 2048 | PROGL1 32  = 378144 u32
    unsigned* R   = (unsigned*)alloc(378144 * 4);
    u16* WlxT0 = (u16*)alloc((size_t)H4 * HH * 2);
    u16* WlhT0 = (u16*)alloc((size_t)H4 * HH * 2);
    u16* WlxT1 = (u16*)alloc((size_t)H4 * HH * 2);
    u16* WlhT1 = (u16*)alloc((size_t)H4 * HH * 2);
    u16* Wo0T  = (u16*)alloc((size_t)HH * HH * 2);
    u16* Wo1T  = (u16*)alloc((size_t)HH * HH * 2);
    u16* W10T  = (u16*)alloc((size_t)H4 * HH * 2);
    u16* W11T  = (u16*)alloc((size_t)H4 * HH * 2);
    u16* W20T  = (u16*)alloc((size_t)HH * H4 * 2);
    u16* W21T  = (u16*)alloc((size_t)HH * H4 * 2);
    u16* embB  = (u16*)alloc((size_t)VV * HH * 2);

    dim3 tb(32, 8);
    // Wl: [L][2H][4H]; rows 0..H-1 = x-part, H..2H-1 = h-part
    transpose_cast<<<dim3(128, 32), tb, 0, stream>>>(Wl, WlxT0, HH, H4);
    transpose_cast<<<dim3(128, 32), tb, 0, stream>>>(Wl + 1024 * 4096, WlhT0, HH, H4);
    transpose_cast<<<dim3(128, 32), tb, 0, stream>>>(Wl + 2048 * 4096, WlxT1, HH, H4);
    transpose_cast<<<dim3(128, 32), tb, 0, stream>>>(Wl + 3072 * 4096, WlhT1, HH, H4);
    transpose_cast<<<dim3(32, 32), tb, 0, stream>>>(Wo, Wo0T, HH, HH);
    transpose_cast<<<dim3(32, 32), tb, 0, stream>>>(Wo + 1024 * 1024, Wo1T, HH, HH);
    transpose_cast<<<dim3(128, 32), tb, 0, stream>>>(W1, W10T, HH, H4);
    transpose_cast<<<dim3(128, 32), tb, 0, stream>>>(W1 + 1024 * 4096, W11T, HH, H4);
    transpose_cast<<<dim3(32, 128), tb, 0, stream>>>(W2, W20T, H4, HH);
    transpose_cast<<<dim3(32, 128), tb, 0, stream>>>(W2 + 4096 * 1024, W21T, H4, HH);
    cast_bf16<<<(VV * HH + 255) / 256, 256, 0, stream>>>(emb, embB, VV * HH);
    gather_ln<<<dim3(TT, BB), 256, 0, stream>>>(x, emb, ln_g, ln_b, xe, xn0);

    // Phase A GEMMs (parallel precompute)
    gemm_bt<0><<<dim3(32, 16), 256, 0, stream>>>(xn0, WlxT0, pre_z0, nullptr, bl, 2048, 4096, 1024);
    gemm_bt<1><<<dim3(32, 16), 256, 0, stream>>>(xn0, W10T, nullptr, U0, b1, 2048, 4096, 1024);
    gemm_bt<0><<<dim3(8, 16), 256, 0, stream>>>(U0, W20T, ff0, nullptr, b2, 2048, 1024, 4096);

    // zero rings + progress
    zero_buf<<<1478, 256, 0, stream>>>((float*)R, 378144);

    // Phase B: 4-stage pipelined recurrence (L0 | Y0/LN | zx1 | L1), sentinel h-rings
    lstm_pipe<<<256, 512, 0, stream>>>(WlhT0, Wo0T, WlxT1, WlhT1, pre_z0, xe, ff0,
                                       ln_g, ln_b, bl, bo, y0_all, xn1, H1bf, R);

    // Phase C: deferred layer-1 output + logits
    gemm_bt<1><<<dim3(32, 16), 256, 0, stream>>>(xn1, W11T, nullptr, U1, b1 + 4096, 2048, 4096, 1024);
    p1_add<<<8192, 256, 0, stream>>>(y0_all, xe, b2 + 1024, bo + 1024);
    gemm_bt<2><<<dim3(8, 16), 256, 0, stream>>>(U1, W21T, y0_all, nullptr, nullptr, 2048, 1024, 4096);
    gemm_bt<2><<<dim3(8, 16), 256, 0, stream>>>(H1bf, Wo1T, y0_all, nullptr, nullptr, 2048, 1024, 1024);
    p2_cast<<<8192, 256, 0, stream>>>(y0_all, Y1bf);
    gemm_bt<3><<<dim3(250, 16), 256, 0, stream>>>(Y1bf, embB, out, nullptr, nullptr, 2048, 32000, 1024);
}

// Round 15
// 3559.521 us; speedup vs baseline: 3.1018x; 1.0228x over previous
//
#include <hip/hip_runtime.h>

typedef unsigned short u16;
typedef short bf16x8 __attribute__((ext_vector_type(8)));
typedef unsigned short ushort8 __attribute__((ext_vector_type(8)));
typedef unsigned short us4 __attribute__((ext_vector_type(4)));
typedef unsigned u32x4 __attribute__((ext_vector_type(4)));
typedef float fx4 __attribute__((ext_vector_type(4)));

#define DEVI __device__ __forceinline__

enum { BB = 4, TT = 512, HH = 1024, VV = 32000, H4 = 4096 };
enum { WSTR = 1032 };  // u16 row stride for LDS weight/stage arrays

DEVI u16 f2bf(float f) {
    union { float f; unsigned u; } x; x.f = f;
    unsigned r = x.u + 0x7fff + ((x.u >> 16) & 1);
    return (u16)(r >> 16);
}
DEVI float bf2f(u16 u) {
    union { unsigned u; float f; } x; x.u = ((unsigned)u) << 16;
    return x.f;
}
DEVI float sigm(float x) { return 1.f / (1.f + __expf(-x)); }
DEVI float tanh_f(float x) {
    float a = fabsf(x);
    float t = 1.f - 2.f / (__expf(2.f * a) + 1.f);
    return x < 0.f ? -t : t;
}

DEVI unsigned ald_u32(const unsigned* p) { return __hip_atomic_load(p, __ATOMIC_RELAXED, __HIP_MEMORY_SCOPE_AGENT); }
DEVI void ast_u32(unsigned* p, unsigned v) { __hip_atomic_store(p, v, __ATOMIC_RELAXED, __HIP_MEMORY_SCOPE_AGENT); }

DEVI void ld4cc(const unsigned* p, u32x4* out) {
    asm volatile("global_load_dwordx4 %0, %1, off sc0 sc1" : "=v"(*out) : "v"(p));
}

// async global->LDS, 16B per lane (dest = wave-uniform base + lane*16)
DEVI void gl_lds16(const u16* g, u16* l) {
    __builtin_amdgcn_global_load_lds((const __attribute__((address_space(1))) unsigned*)g,
                                     (__attribute__((address_space(3))) unsigned*)l, 16, 0, 0);
}

// ---- sentinel hop protocol (h rings) ----
template <int SLP>
DEVI void sent_poll(const unsigned* sbase, unsigned want, int lane) {
    const unsigned* p = sbase + lane;
    unsigned v = ald_u32(p);
    while (v != want) { __builtin_amdgcn_s_sleep(SLP); v = ald_u32(p); }
}
// all-thread payload fetch: 1 dwordx4 (8 bf16) -> stg
DEVI void data_fetch(const unsigned* dbase, u16* st, int tid) {
    u32x4 d;
    ld4cc(dbase + tid * 4, &d);
    asm volatile("s_waitcnt vmcnt(0)" ::: "memory");
    __builtin_amdgcn_sched_barrier(0);
    int wi = tid * 8;
    u16* dst = st + (wi >> 10) * WSTR + (wi & 1023);
    *(us4*)dst       = (us4){(u16)d[0], (u16)(d[0] >> 16), (u16)d[1], (u16)(d[1] >> 16)};
    *(us4*)(dst + 4) = (us4){(u16)d[2], (u16)(d[2] >> 16), (u16)d[3], (u16)(d[3] >> 16)};
}

// poll a 4096-word tagged region ([4][1024] b-major) into LDS st[4][WSTR]
template <int SLP>
DEVI void poll4096(const unsigned* base, unsigned want, u16* st, int tid) {
    const unsigned* p0 = base + tid * 8;
    const unsigned* p1 = p0 + 4;
    u32x4 v0, v1;
    ld4cc(p0, &v0); ld4cc(p1, &v1);
    asm volatile("s_waitcnt vmcnt(0)" ::: "memory");
    __builtin_amdgcn_sched_barrier(0);
    for (;;) {
        bool o0 = ((v0[0]>>16)==want)&((v0[1]>>16)==want)&((v0[2]>>16)==want)&((v0[3]>>16)==want);
        bool o1 = ((v1[0]>>16)==want)&((v1[1]>>16)==want)&((v1[2]>>16)==want)&((v1[3]>>16)==want);
        if (o0 & o1) break;
        __builtin_amdgcn_s_sleep(SLP);
        if (!o0) ld4cc(p0, &v0);
        if (!o1) ld4cc(p1, &v1);
        asm volatile("s_waitcnt vmcnt(0)" ::: "memory");
        __builtin_amdgcn_sched_barrier(0);
    }
    int wi = tid * 8;
    u16* d = st + (wi >> 10) * WSTR + (wi & 1023);
    *(us4*)d       = (us4){(u16)v0[0], (u16)v0[1], (u16)v0[2], (u16)v0[3]};
    *(us4*)(d + 4) = (us4){(u16)v1[0], (u16)v1[1], (u16)v1[2], (u16)v1[3]};
}

DEVI unsigned poll_word(const unsigned* p, unsigned want) {
    unsigned v = ald_u32(p);
    while ((v >> 16) != want) { __builtin_amdgcn_s_sleep(2); v = ald_u32(p); }
    return v & 0xFFFFu;
}

// 64-row gate MFMA: D[64 rows][4 cols] = W(LDS) @ h(LDS bf16)
DEVI void gates64(const u16* wl, const u16* st, float* fb, int tid) {
    int lane = tid & 63, wv = tid >> 6;
    int rt = wv & 3, kh = wv >> 2;
    fx4 acc = {0.f, 0.f, 0.f, 0.f};
    int aoff = (rt * 16 + (lane & 15)) * WSTR + (lane >> 4) * 8;
    int boff = (lane & 3) * WSTR + (lane >> 4) * 8;
#pragma unroll
    for (int kt = 0; kt < 16; kt++) {
        int k0 = (kh * 16 + kt) * 32;
        bf16x8 a = *(const bf16x8*)(wl + aoff + k0);
        bf16x8 b = *(const bf16x8*)(st + boff + k0);
        acc = __builtin_amdgcn_mfma_f32_16x16x32_bf16(a, b, acc, 0, 0, 0);
    }
    int col = lane & 15;
    if (col < 4) {
        int r0 = rt * 16 + (lane >> 4) * 4;
#pragma unroll
        for (int ri = 0; ri < 4; ri++) fb[kh * 256 + (r0 + ri) * 4 + col] = acc[ri];
    }
}

// ---------------- transpose + cast: src [R][C] f32 -> dst [C][R] bf16 ----------------
__global__ void transpose_cast(const float* __restrict__ src, u16* __restrict__ dst, int R, int C) {
    __shared__ float tile[32][33];
    int c0 = blockIdx.x * 32, r0 = blockIdx.y * 32;
    int x = threadIdx.x, y = threadIdx.y;
#pragma unroll
    for (int i = 0; i < 32; i += 8) tile[y + i][x] = src[(size_t)(r0 + y + i) * C + c0 + x];
    __syncthreads();
#pragma unroll
    for (int i = 0; i < 32; i += 8) dst[(size_t)(c0 + y + i) * R + r0 + x] = f2bf(tile[x][y + i]);
}

__global__ void cast_bf16(const float* __restrict__ src, u16* __restrict__ dst, int n) {
    int i = blockIdx.x * 256 + threadIdx.x;
    if (i < n) dst[i] = f2bf(src[i]);
}

__global__ void zero_buf(float* p, int n) {
    int i = blockIdx.x * 256 + threadIdx.x;
    if (i < n) p[i] = 0.f;
}

// ---------------- gather + layernorm (layer 0 input) ----------------
__global__ __launch_bounds__(256) void gather_ln(const int* __restrict__ x, const float* __restrict__ emb,
                                                 const float* __restrict__ g, const float* __restrict__ b,
                                                 float* __restrict__ xe, u16* __restrict__ xn0) {
    int t = blockIdx.x, bb = blockIdx.y;
    int row = x[bb * TT + t];
    const float* e = emb + (size_t)row * HH;
    float v[4]; float s = 0.f, s2 = 0.f;
#pragma unroll
    for (int p = 0; p < 4; p++) { v[p] = e[p * 256 + threadIdx.x]; s += v[p]; s2 += v[p] * v[p]; }
    __shared__ float ls[4], ls2[4];
    for (int off = 32; off; off >>= 1) { s += __shfl_xor(s, off); s2 += __shfl_xor(s2, off); }
    int w = threadIdx.x >> 6, lane = threadIdx.x & 63;
    if (lane == 0) { ls[w] = s; ls2[w] = s2; }
    __syncthreads();
    s = ls[0] + ls[1] + ls[2] + ls[3];
    s2 = ls2[0] + ls2[1] + ls2[2] + ls2[3];
    float mu = s * (1.f / HH);
    float var = s2 * (1.f / HH) - mu * mu;
    float rs = rsqrtf(var + 1e-6f);
    size_t base = ((size_t)t * BB + bb) * HH;
#pragma unroll
    for (int p = 0; p < 4; p++) {
        int j = p * 256 + threadIdx.x;
        xe[base + j] = v[p];
        xn0[base + j] = f2bf((v[p] - mu) * rs * g[j] + b[j]);
    }
}

// ---------------- MFMA GEMM (global_load_lds staging): C[M,N] = A[M,K] * Bt[N,K]^T ----
// MODE 0: Cf = v + bias[gc]
// MODE 1: Cb = bf16(relu(v + bias[gc]))
// MODE 3: logits remap: out[b*T*V + t*V + gc] = v
// MODE 4: Cf += v + addf[idx] + bias[gc] + bias2[gc]
// MODE 5: Cb = bf16(Cf[idx] + v)
template <int MODE>
__global__ __launch_bounds__(256) void gemm_bt(const u16* __restrict__ A, const u16* __restrict__ Bt,
                                               float* __restrict__ Cf, u16* __restrict__ Cb,
                                               const float* __restrict__ bias, const float* __restrict__ bias2,
                                               const float* __restrict__ addf, int M, int N, int K) {
    __shared__ u16 ldsA[128 * 32];
    __shared__ u16 ldsB[128 * 32];
    const int tid = threadIdx.x;
    const int m0 = blockIdx.y * 128, n0 = blockIdx.x * 128;
    const int lane = tid & 63, wid = tid >> 6;
    const int wr = wid >> 1, wc = wid & 1;
    const int l15 = lane & 15, lk = (lane >> 4) * 8;
    fx4 acc[4][4];
#pragma unroll
    for (int a = 0; a < 4; a++)
#pragma unroll
        for (int b = 0; b < 4; b++) { fx4 z = {0.f, 0.f, 0.f, 0.f}; acc[a][b] = z; }

    const int srow = lane >> 2, scol = (lane & 3) * 8;   // within 16-row slab
    const int i0 = wid * 32;                             // rows staged by this wave
    for (int k0 = 0; k0 < K; k0 += 32) {
        gl_lds16(A + (size_t)(m0 + i0 + srow) * K + k0 + scol,       &ldsA[i0 * 32]);
        gl_lds16(A + (size_t)(m0 + i0 + 16 + srow) * K + k0 + scol,  &ldsA[(i0 + 16) * 32]);
        gl_lds16(Bt + (size_t)(n0 + i0 + srow) * K + k0 + scol,      &ldsB[i0 * 32]);
        gl_lds16(Bt + (size_t)(n0 + i0 + 16 + srow) * K + k0 + scol, &ldsB[(i0 + 16) * 32]);
        __syncthreads();
        bf16x8 af[4], bfr[4];
#pragma unroll
        for (int mi = 0; mi < 4; mi++) af[mi] = *(const bf16x8*)&ldsA[(wr * 64 + mi * 16 + l15) * 32 + lk];
#pragma unroll
        for (int ni = 0; ni < 4; ni++) bfr[ni] = *(const bf16x8*)&ldsB[(wc * 64 + ni * 16 + l15) * 32 + lk];
#pragma unroll
        for (int mi = 0; mi < 4; mi++)
#pragma unroll
            for (int ni = 0; ni < 4; ni++)
                acc[mi][ni] = __builtin_amdgcn_mfma_f32_16x16x32_bf16(af[mi], bfr[ni], acc[mi][ni], 0, 0, 0);
        __syncthreads();
    }
#pragma unroll
    for (int mi = 0; mi < 4; mi++) {
#pragma unroll
        for (int ni = 0; ni < 4; ni++) {
#pragma unroll
            for (int r = 0; r < 4; r++) {
                int gr = m0 + wr * 64 + mi * 16 + (lane >> 4) * 4 + r;
                int gc = n0 + wc * 64 + ni * 16 + l15;
                float v = acc[mi][ni][r];
                size_t idx = (size_t)gr * N + gc;
                if (MODE == 0) {
                    Cf[idx] = v + bias[gc];
                } else if (MODE == 1) {
                    float u = v + bias[gc];
                    Cb[idx] = f2bf(u > 0.f ? u : 0.f);
                } else if (MODE == 3) {
                    int b = gr & 3, t = gr >> 2;
                    Cf[((size_t)b * TT + t) * VV + gc] = v;
                } else if (MODE == 4) {
                    Cf[idx] += v + addf[idx] + bias[gc] + bias2[gc];
                } else {  // MODE 5
                    Cb[idx] = f2bf(Cf[idx] + v);
                }
            }
        }
    }
}

// ---------------- Phase B: 4-stage pipelined dataflow, sentinel h-rings ----------------
// R (u32): RD0[16][2048] | RS0[16][64] | RD1[4][2048] | RS1[4][64] | RPART[4][1024]
//          | RXN[16][4096] | RZX[16][16384] | PROGY | PROGZX | PROGL1
// Roles: 0-63 L0 chain | 64-127 Y0/LN | 128-191 zx1 | 192-255 L1 chain.
__global__ __launch_bounds__(512, 1) void lstm_pipe(
    const u16* __restrict__ Wh0T, const u16* __restrict__ Wo0T,
    const u16* __restrict__ Wx1T, const u16* __restrict__ Wh1T,
    const float* __restrict__ pz_all, const float* __restrict__ xe, const float* __restrict__ ff0,
    const float* __restrict__ lng, const float* __restrict__ lnb,
    const float* __restrict__ bl, const float* __restrict__ bo,
    float* __restrict__ y0_all, u16* __restrict__ xn1, u16* __restrict__ H1bf,
    unsigned* __restrict__ R) {
    __shared__ u16 wlds[64 * WSTR];   // 129 KB weights
    __shared__ u16 stg[4 * WSTR];     // 8.1 KB staged vector (bf16)
    __shared__ float fb[1664];

    const int bid = blockIdx.x;
    const int tid = threadIdx.x;
    const int lane = tid & 63, wv = tid >> 6;

    unsigned* RD0 = R;
    unsigned* RS0 = R + 32768;
    unsigned* RD1 = R + 33792;
    unsigned* RS1 = R + 41984;
    unsigned* RPART = R + 42240;
    unsigned* RXN = R + 46336;
    unsigned* RZX = R + 111872;
    unsigned* PROGY = R + 374016;
    unsigned* PROGZX = R + 376064;
    unsigned* PROGL1 = R + 378112;

    if (bid < 64) {
        // ================= L0 chain (gates only, sentinel ring-16) =================
        const int w = bid;
        {
            int row = tid >> 3, kc = tid & 7;
            int gr = (row >> 4) * 1024 + w * 16 + (row & 15);
            const uint4* s = (const uint4*)(Wh0T + (size_t)gr * 1024 + kc * 128);
            uint4* d = (uint4*)(wlds + row * WSTR + kc * 128);
#pragma unroll
            for (int i = 0; i < 16; i++) d[i] = s[i];
        }
        if (tid < 64) fb[1024 + tid] = 0.f;   // c-state
        __syncthreads();

        for (int s = 0; s < TT; s++) {
            if ((s & 7) == 0 && wv == 1) {   // ring-16 guard vs Y0 lag (wave 1, overlaps sentinel poll)
                for (;;) {
                    unsigned p = ald_u32(PROGY + lane * 32);
#pragma unroll
                    for (int off = 1; off < 64; off <<= 1) {
                        unsigned o = (unsigned)__shfl_xor((int)p, off);
                        p = p < o ? p : o;
                    }
                    if ((int)p >= s - 8) break;
                    __builtin_amdgcn_s_sleep(8);
                }
            }
            float pzv[4] = {0.f, 0.f, 0.f, 0.f};
            if (tid < 64) {
                int x = tid >> 2, b = tid & 3;
#pragma unroll
                for (int g = 0; g < 4; g++)
                    pzv[g] = pz_all[((size_t)s * 4 + b) * 4096 + g * 1024 + w * 16 + x];
            }
            if (wv == 0) sent_poll<1>(RS0 + ((s + 15) & 15) * 64, (unsigned)s, lane);
            __syncthreads();   // bS: h0[s-1] published (+ throttle done)
            data_fetch(RD0 + ((s + 15) & 15) * 2048, stg, tid);
            __syncthreads();   // b1: stg ready
            float* gbuf = fb + (s & 1) * 512;
            gates64(wlds, stg, gbuf, tid);
            __syncthreads();   // b2: gbuf ready
            if (tid < 64) {
                int x = tid >> 2, b = tid & 3;
                float z0 = gbuf[(0*16+x)*4+b] + gbuf[256+(0*16+x)*4+b] + pzv[0];
                float z1 = gbuf[(1*16+x)*4+b] + gbuf[256+(1*16+x)*4+b] + pzv[1];
                float z2 = gbuf[(2*16+x)*4+b] + gbuf[256+(2*16+x)*4+b] + pzv[2];
                float z3 = gbuf[(3*16+x)*4+b] + gbuf[256+(3*16+x)*4+b] + pzv[3];
                float ig = sigm(z0), fg = sigm(z1), og = sigm(z2), gg = tanh_f(z3);
                float c = fg * fb[1024 + tid] + ig * gg;
                fb[1024 + tid] = c;
                float h = og * tanh_f(c);
                float hn = __shfl(h, (tid + 4) & 63);
                if (((tid >> 2) & 1) == 0) {
                    unsigned word = (unsigned)f2bf(h) | ((unsigned)f2bf(hn) << 16);
                    ast_u32(&RD0[(s & 15) * 2048 + b * 512 + w * 8 + (x >> 1)], word);
                }
                asm volatile("s_waitcnt vmcnt(0)" ::: "memory");
                if (tid == 0) ast_u32(&RS0[(s & 15) * 64 + w], (unsigned)(s + 1));
            }
        }
    } else if (bid < 128) {
        // ================= Y0 / LN stage =================
        const int wy = bid - 64;
        {
            int row = tid >> 5, kc = tid & 31;
            const uint4* s = (const uint4*)(Wo0T + (size_t)(wy * 16 + row) * 1024 + kc * 32);
            uint4* d = (uint4*)(wlds + row * WSTR + kc * 32);
            d[0] = s[0]; d[1] = s[1]; d[2] = s[2]; d[3] = s[3];
        }
        float lgR = 0.f, lbR = 0.f, boR = 0.f;
        if (tid < 64) {
            int x = tid >> 2;
            lgR = lng[1024 + wy * 16 + x];
            lbR = lnb[1024 + wy * 16 + x];
            boR = bo[wy * 16 + x];
        }
        __syncthreads();

        for (int t = 0; t <= TT; t++) {
            const bool doDot = (t < TT);
            const bool doLN = (t >= 1);
            if ((t & 7) == 0 && wv == 1) {   // RXN ring-16 guard vs zx lag (wave 1)
                for (;;) {
                    unsigned p = ald_u32(PROGZX + lane * 32);
#pragma unroll
                    for (int off = 1; off < 64; off <<= 1) {
                        unsigned o = (unsigned)__shfl_xor((int)p, off);
                        p = p < o ? p : o;
                    }
                    if ((int)p >= t - 8) break;
                    __builtin_amdgcn_s_sleep(8);
                }
            }
            float xev = 0.f, ffv = 0.f;
            if (doDot && tid < 64) {
                int x = tid >> 2, b = tid & 3;
                size_t base = ((size_t)t * 4 + b) * 1024 + wy * 16 + x;
                xev = xe[base]; ffv = ff0[base];
            }
            if (doDot && wv == 0) sent_poll<4>(RS0 + (t & 15) * 64, (unsigned)(t + 1), lane);
            __syncthreads();   // bS
            if (doDot) data_fetch(RD0 + (t & 15) * 2048, stg, tid);
            if (doLN) {
                const unsigned* p = RPART + ((t - 1) & 3) * 1024 + tid * 2;
                unsigned hi = poll_word(p, (unsigned)t);
                unsigned lo = poll_word(p + 1, (unsigned)t);
                union { unsigned u; float f; } cv; cv.u = (hi << 16) | lo;
                fb[tid] = cv.f;
            }
            __syncthreads();   // b1: stg + fbP ready
            if (doDot && tid == 0) ast_u32(PROGY + wy * 32, (unsigned)(t + 1));
            if (doLN && tid < 8) {
                int b = tid & 3, kind = tid >> 2;
                float S = 0.f;
                for (int i = 0; i < 64; i++) S += fb[i * 8 + b * 2 + kind];
                fb[704 + kind * 4 + b] = S;
            }
            if (doDot) {
                int out = tid >> 3, c = tid & 7;
                const u16* wrow = wlds + (out >> 2) * WSTR + c * 128;
                const u16* hrow = stg + (out & 3) * WSTR + c * 128;
                float acc = 0.f;
#pragma unroll
                for (int m = 0; m < 16; m++) {
                    ushort8 w8 = *(const ushort8*)(wrow + m * 8);
                    ushort8 h8 = *(const ushort8*)(hrow + m * 8);
#pragma unroll
                    for (int q = 0; q < 8; q++) acc += bf2f(w8[q]) * bf2f(h8[q]);
                }
                acc += __shfl_xor(acc, 1); acc += __shfl_xor(acc, 2); acc += __shfl_xor(acc, 4);
                if (c == 0) fb[512 + out] = acc;
            }
            __syncthreads();   // b2
            if (doDot && tid < 64) {
                int x = tid >> 2, b = tid & 3;
                float y = fb[512 + tid] + xev + ffv + boR;
                y0_all[((size_t)t * 4 + b) * 1024 + wy * 16 + x] = y;
                fb[576 + (t & 1) * 64 + tid] = y;
                float sv = y, sq = y * y;
#pragma unroll
                for (int off = 4; off < 64; off <<= 1) { sv += __shfl_xor(sv, off); sq += __shfl_xor(sq, off); }
                if (tid < 4) {
                    unsigned tg = (unsigned)(t + 1) << 16;
                    unsigned* pb = RPART + (t & 3) * 1024 + wy * 16 + tid * 4;
                    union { float f; unsigned u; } c1, c2; c1.f = sv; c2.f = sq;
                    ast_u32(pb + 0, tg | (c1.u >> 16));
                    ast_u32(pb + 1, tg | (c1.u & 0xFFFFu));
                    ast_u32(pb + 2, tg | (c2.u >> 16));
                    ast_u32(pb + 3, tg | (c2.u & 0xFFFFu));
                }
            }
            __syncthreads();   // b3
            if (doLN && tid < 64) {
                int x = tid >> 2, b = tid & 3;
                int u = t - 1;
                float mu = fb[704 + b] * (1.f / 1024.f);
                float rs = rsqrtf(fb[708 + b] * (1.f / 1024.f) - mu * mu + 1e-6f);
                float yv = fb[576 + (u & 1) * 64 + tid];
                float xnv = (yv - mu) * rs * lgR + lbR;
                u16 xb = f2bf(xnv);
                xn1[(size_t)u * 4096 + b * 1024 + wy * 16 + x] = xb;
                ast_u32(&RXN[(u & 15) * 4096 + b * 1024 + wy * 16 + x],
                        ((unsigned)(u + 1) << 16) | xb);
            }
        }
    } else if (bid < 192) {
        // ================= zx1 group =================
        const int wz = bid - 128;
        {
            int row = tid >> 3, kc = tid & 7;
            int gr = (row >> 4) * 1024 + wz * 16 + (row & 15);
            const uint4* s = (const uint4*)(Wx1T + (size_t)gr * 1024 + kc * 128);
            uint4* d = (uint4*)(wlds + row * WSTR + kc * 128);
#pragma unroll
            for (int i = 0; i < 16; i++) d[i] = s[i];
        }
        if (tid < 64) fb[1536 + tid] = bl[4096 + (tid >> 4) * 1024 + wz * 16 + (tid & 15)];
        __syncthreads();

        for (int t = 0; t < TT; t++) {
            if ((t & 7) == 0 && tid == 0) {
                while ((int)ald_u32(PROGL1) < t - 6) __builtin_amdgcn_s_sleep(8);
            }
            poll4096<8>(RXN + (t & 15) * 4096, (unsigned)(t + 1), stg, tid);
            __syncthreads();
            gates64(wlds, stg, fb, tid);
            __syncthreads();
            if (tid == 0) ast_u32(PROGZX + wz * 32, (unsigned)(t + 1));
            if (tid < 256) {
                int lr = tid >> 2, b = tid & 3;
                float v = fb[lr * 4 + b] + fb[256 + lr * 4 + b] + fb[1536 + lr];
                ast_u32(&RZX[(t & 15) * 16384 + wz * 256 + tid],
                        ((unsigned)(t + 1) << 16) | f2bf(v));
            }
            __syncthreads();
        }
    } else {
        // ================= L1 chain (sentinel ring-4) =================
        const int w1 = bid - 192;
        {
            int row = tid >> 3, kc = tid & 7;
            int gr = (row >> 4) * 1024 + w1 * 16 + (row & 15);
            const uint4* s = (const uint4*)(Wh1T + (size_t)gr * 1024 + kc * 128);
            uint4* d = (uint4*)(wlds + row * WSTR + kc * 128);
#pragma unroll
            for (int i = 0; i < 16; i++) d[i] = s[i];
        }
        if (tid < 64) fb[1600 + tid] = 0.f;   // c-state
        __syncthreads();

        for (int v = 0; v < TT; v++) {
            if (tid < 256) {
                const unsigned* p = RZX + (v & 15) * 16384 + w1 * 256 + tid;
                fb[1024 + (v & 1) * 256 + tid] = bf2f((u16)poll_word(p, (unsigned)(v + 1)));
            }
            if (wv == 0) sent_poll<1>(RS1 + ((v + 3) & 3) * 64, (unsigned)v, lane);
            __syncthreads();   // bS
            data_fetch(RD1 + ((v + 3) & 3) * 2048, stg, tid);
            __syncthreads();   // b1
            if (bid == 192 && tid == 0) ast_u32(PROGL1, (unsigned)(v + 1));
            float* gbuf = fb + (v & 1) * 512;
            gates64(wlds, stg, gbuf, tid);
            __syncthreads();   // b2
            if (tid < 64) {
                int x = tid >> 2, b = tid & 3;
                const float* zb = fb + 1024 + (v & 1) * 256;
                float z0 = gbuf[(0*16+x)*4+b] + gbuf[256+(0*16+x)*4+b] + zb[(0*16+x)*4+b];
                float z1 = gbuf[(1*16+x)*4+b] + gbuf[256+(1*16+x)*4+b] + zb[(1*16+x)*4+b];
                float z2 = gbuf[(2*16+x)*4+b] + gbuf[256+(2*16+x)*4+b] + zb[(2*16+x)*4+b];
                float z3 = gbuf[(3*16+x)*4+b] + gbuf[256+(3*16+x)*4+b] + zb[(3*16+x)*4+b];
                float ig = sigm(z0), fg = sigm(z1), og = sigm(z2), gg = tanh_f(z3);
                float c = fg * fb[1600 + tid] + ig * gg;
                fb[1600 + tid] = c;
                float h = og * tanh_f(c);
                u16 hb = f2bf(h);
                H1bf[(size_t)v * 4096 + b * 1024 + w1 * 16 + x] = hb;
                float hn = __shfl(h, (tid + 4) & 63);
                if (((tid >> 2) & 1) == 0) {
                    unsigned word = (unsigned)hb | ((unsigned)f2bf(hn) << 16);
                    ast_u32(&RD1[(v & 3) * 2048 + b * 512 + w1 * 8 + ((tid >> 2) >> 1)], word);
                }
                asm volatile("s_waitcnt vmcnt(0)" ::: "memory");
                if (tid == 0) ast_u32(&RS1[(v & 3) * 64 + w1], (unsigned)(v + 1));
            }
        }
    }
}

// ---------------- host ----------------
extern "C" void kernel_launch(void* const* d_in, const int* in_sizes, int n_in,
                              void* d_out, int out_size, void* d_ws, size_t ws_size,
                              hipStream_t stream) {
    const int* x = (const int*)d_in[0];
    const float* emb = (const float*)d_in[1];
    const float* ln_g = (const float*)d_in[2];
    const float* ln_b = (const float*)d_in[3];
    const float* Wl = (const float*)d_in[4];
    const float* bl = (const float*)d_in[5];
    const float* Wo = (const float*)d_in[6];
    const float* bo = (const float*)d_in[7];
    const float* W1 = (const float*)d_in[8];
    const float* b1 = (const float*)d_in[9];
    const float* W2 = (const float*)d_in[10];
    const float* b2 = (const float*)d_in[11];
    float* out = (float*)d_out;

    char* wp = (char*)d_ws;
    auto alloc = [&](size_t bytes) { void* p = wp; wp += (bytes + 255) & ~(size_t)255; return p; };
    const size_t MBT = (size_t)TT * BB;  // 2048 rows
    float* xe     = (float*)alloc(MBT * HH * 4);
    float* pre_z0 = (float*)alloc(MBT * H4 * 4);
    float* ff0    = (float*)alloc(MBT * HH * 4);
    float* y0_all = (float*)alloc(MBT * HH * 4);
    u16* xn0      = (u16*)alloc(MBT * HH * 2);
    u16* xn1      = (u16*)alloc(MBT * HH * 2);
    u16* U0       = (u16*)alloc(MBT * H4 * 2);
    u16* U1       = (u16*)alloc(MBT * H4 * 2);
    u16* H1bf     = (u16*)alloc(MBT * HH * 2);
    u16* Y1bf     = (u16*)alloc(MBT * HH * 2);
    unsigned* R   = (unsigned*)alloc(378144 * 4);
    u16* WlxT0 = (u16*)alloc((size_t)H4 * HH * 2);
    u16* WlhT0 = (u16*)alloc((size_t)H4 * HH * 2);
    u16* WlxT1 = (u16*)alloc((size_t)H4 * HH * 2);
    u16* WlhT1 = (u16*)alloc((size_t)H4 * HH * 2);
    u16* Wo0T  = (u16*)alloc((size_t)HH * HH * 2);
    u16* Wo1T  = (u16*)alloc((size_t)HH * HH * 2);
    u16* W10T  = (u16*)alloc((size_t)H4 * HH * 2);
    u16* W11T  = (u16*)alloc((size_t)H4 * HH * 2);
    u16* W20T  = (u16*)alloc((size_t)HH * H4 * 2);
    u16* W21T  = (u16*)alloc((size_t)HH * H4 * 2);
    u16* embB  = (u16*)alloc((size_t)VV * HH * 2);

    dim3 tb(32, 8);
    // Wl: [L][2H][4H]; rows 0..H-1 = x-part, H..2H-1 = h-part
    transpose_cast<<<dim3(128, 32), tb, 0, stream>>>(Wl, WlxT0, HH, H4);
    transpose_cast<<<dim3(128, 32), tb, 0, stream>>>(Wl + 1024 * 4096, WlhT0, HH, H4);
    transpose_cast<<<dim3(128, 32), tb, 0, stream>>>(Wl + 2048 * 4096, WlxT1, HH, H4);
    transpose_cast<<<dim3(128, 32), tb, 0, stream>>>(Wl + 3072 * 4096, WlhT1, HH, H4);
    transpose_cast<<<dim3(32, 32), tb, 0, stream>>>(Wo, Wo0T, HH, HH);
    transpose_cast<<<dim3(32, 32), tb, 0, stream>>>(Wo + 1024 * 1024, Wo1T, HH, HH);
    transpose_cast<<<dim3(128, 32), tb, 0, stream>>>(W1, W10T, HH, H4);
    transpose_cast<<<dim3(128, 32), tb, 0, stream>>>(W1 + 1024 * 4096, W11T, HH, H4);
    transpose_cast<<<dim3(32, 128), tb, 0, stream>>>(W2, W20T, H4, HH);
    transpose_cast<<<dim3(32, 128), tb, 0, stream>>>(W2 + 4096 * 1024, W21T, H4, HH);
    cast_bf16<<<(VV * HH + 255) / 256, 256, 0, stream>>>(emb, embB, VV * HH);
    gather_ln<<<dim3(TT, BB), 256, 0, stream>>>(x, emb, ln_g, ln_b, xe, xn0);

    // Phase A GEMMs (parallel precompute)
    gemm_bt<0><<<dim3(32, 16), 256, 0, stream>>>(xn0, WlxT0, pre_z0, nullptr, bl, nullptr, nullptr, 2048, 4096, 1024);
    gemm_bt<1><<<dim3(32, 16), 256, 0, stream>>>(xn0, W10T, nullptr, U0, b1, nullptr, nullptr, 2048, 4096, 1024);
    gemm_bt<0><<<dim3(8, 16), 256, 0, stream>>>(U0, W20T, ff0, nullptr, b2, nullptr, nullptr, 2048, 1024, 4096);

    // zero rings + progress
    zero_buf<<<1478, 256, 0, stream>>>((float*)R, 378144);

    // Phase B: 4-stage pipelined recurrence (L0 | Y0/LN | zx1 | L1), sentinel h-rings
    lstm_pipe<<<256, 512, 0, stream>>>(WlhT0, Wo0T, WlxT1, WlhT1, pre_z0, xe, ff0,
                                       ln_g, ln_b, bl, bo, y0_all, xn1, H1bf, R);

    // Phase C: deferred layer-1 output + logits (fused epilogues)
    gemm_bt<1><<<dim3(32, 16), 256, 0, stream>>>(xn1, W11T, nullptr, U1, b1 + 4096, nullptr, nullptr, 2048, 4096, 1024);
    gemm_bt<4><<<dim3(8, 16), 256, 0, stream>>>(U1, W21T, y0_all, nullptr, b2 + 1024, bo + 1024, xe, 2048, 1024, 4096);
    gemm_bt<5><<<dim3(8, 16), 256, 0, stream>>>(H1bf, Wo1T, y0_all, Y1bf, nullptr, nullptr, nullptr, 2048, 1024, 1024);
    gemm_bt<3><<<dim3(250, 16), 256, 0, stream>>>(Y1bf, embB, out, nullptr, nullptr, nullptr, nullptr, 2048, 32000, 1024);
}